// Round 1
// baseline (630.757 us; speedup 1.0000x reference)
//
#include <hip/hip_runtime.h>

#define N_NODES 100000
#define N_EDGES 1600000
#define D 64

// ---------------- Phase A: zero workspace ----------------
__global__ __launch_bounds__(256) void zero_ws_kernel(float* __restrict__ ws, int n) {
    int stride = gridDim.x * blockDim.x;
    for (int i = blockIdx.x * blockDim.x + threadIdx.x; i < n; i += stride)
        ws[i] = 0.0f;
}

// ---------------- Phase B: scatter-add (one wave per edge) ----------------
__global__ __launch_bounds__(256) void scatter_kernel(const float* __restrict__ x,
                                                      const int*   __restrict__ ei,
                                                      float* __restrict__ agg,
                                                      float* __restrict__ cnt) {
    const int lane = threadIdx.x & 63;
    const int e    = blockIdx.x * (blockDim.x >> 6) + (threadIdx.x >> 6);
    if (e >= N_EDGES) return;
    const int src = ei[e];
    const int dst = ei[N_EDGES + e];
    const float v = x[src * D + lane];
    atomicAdd(&agg[dst * D + lane], v);
    if (lane == 0) atomicAdd(&cnt[dst], 1.0f);
}

// ---------------- Phase C: mean + dual matmul + bias + ReLU ----------------
// One wave per node row. W_l, W_r, b_l staged in LDS.
__global__ __launch_bounds__(256) void out_kernel(const float* __restrict__ x,
                                                  const float* __restrict__ agg,
                                                  const float* __restrict__ cnt,
                                                  const float* __restrict__ Wl,
                                                  const float* __restrict__ bl,
                                                  const float* __restrict__ Wr,
                                                  float* __restrict__ out) {
    __shared__ float sWl[D * D];
    __shared__ float sWr[D * D];
    __shared__ float sbl[D];
    for (int i = threadIdx.x; i < D * D; i += blockDim.x) {
        sWl[i] = Wl[i];
        sWr[i] = Wr[i];
    }
    if (threadIdx.x < D) sbl[threadIdx.x] = bl[threadIdx.x];
    __syncthreads();

    const int lane = threadIdx.x & 63;
    const int row  = blockIdx.x * (blockDim.x >> 6) + (threadIdx.x >> 6);
    if (row >= N_NODES) return;

    const float c   = cnt[row];
    const float inv = 1.0f / fmaxf(c, 1.0f);
    const float m   = agg[row * D + lane] * inv;   // mean_nbr[row][lane]
    const float xv  = x[row * D + lane];           // x[row][lane]

    float acc = sbl[lane];
    #pragma unroll
    for (int k = 0; k < D; ++k) {
        const float mk = __shfl(m, k);
        const float xk = __shfl(xv, k);
        acc += mk * sWl[k * D + lane] + xk * sWr[k * D + lane];
    }
    out[row * D + lane] = fmaxf(acc, 0.0f);
}

// ---------------- launch ----------------
extern "C" void kernel_launch(void* const* d_in, const int* in_sizes, int n_in,
                              void* d_out, int out_size, void* d_ws, size_t ws_size,
                              hipStream_t stream) {
    const float* x  = (const float*)d_in[0];
    const int*   ei = (const int*)d_in[1];    // [2, N_EDGES] flat: src then dst
    const float* Wl = (const float*)d_in[2];
    const float* bl = (const float*)d_in[3];
    const float* Wr = (const float*)d_in[4];
    float* out = (float*)d_out;

    float* agg = (float*)d_ws;                 // N_NODES * D floats
    float* cnt = agg + (size_t)N_NODES * D;    // N_NODES floats

    // Phase A: zero agg + cnt (6.5M floats)
    {
        const int n = N_NODES * D + N_NODES;
        zero_ws_kernel<<<2048, 256, 0, stream>>>(agg, n);
    }
    // Phase B: scatter-add, one wave per edge, 4 edges per 256-thread block
    {
        const int edges_per_block = 256 / 64;
        const int blocks = (N_EDGES + edges_per_block - 1) / edges_per_block;
        scatter_kernel<<<blocks, 256, 0, stream>>>(x, ei, agg, cnt);
    }
    // Phase C: one wave per row
    {
        const int rows_per_block = 256 / 64;
        const int blocks = (N_NODES + rows_per_block - 1) / rows_per_block;
        out_kernel<<<blocks, 256, 0, stream>>>(x, agg, cnt, Wl, bl, Wr, out);
    }
}

// Round 3
// 501.295 us; speedup vs baseline: 1.2583x; 1.2583x over previous
//
#include <hip/hip_runtime.h>

#define N_NODES 100000
#define N_EDGES 1600000
#define D 64
#define SCAN_B 256
#define NB ((N_NODES + SCAN_B - 1) / SCAN_B)   // 391

// bit-preserving float lane-broadcast (readlane keeps it off the LDS pipe)
__device__ __forceinline__ float lane_read_f(float v, int l) {
    union { float f; int i; } u; u.f = v;
    union { int i; float f; } w; w.i = __builtin_amdgcn_readlane(u.i, l);
    return w.f;
}

// ---------------- histogram of dst ----------------
__global__ __launch_bounds__(256) void hist_kernel(const int* __restrict__ ei,
                                                   int* __restrict__ deg) {
    int stride = gridDim.x * blockDim.x;
    for (int e = blockIdx.x * blockDim.x + threadIdx.x; e < N_EDGES; e += stride) {
        int dst = ei[N_EDGES + e];
        atomicAdd(&deg[dst], 1);
    }
}

// ---------------- scan pass 1: per-block exclusive scan ----------------
__global__ __launch_bounds__(SCAN_B) void scan1_kernel(const int* __restrict__ deg,
                                                       int* __restrict__ tmpExc,
                                                       int* __restrict__ blockSums) {
    __shared__ int s[SCAN_B];
    int i = blockIdx.x * SCAN_B + threadIdx.x;
    int v = (i < N_NODES) ? deg[i] : 0;
    s[threadIdx.x] = v;
    __syncthreads();
    for (int off = 1; off < SCAN_B; off <<= 1) {
        int t = (threadIdx.x >= off) ? s[threadIdx.x - off] : 0;
        __syncthreads();
        s[threadIdx.x] += t;
        __syncthreads();
    }
    if (i < N_NODES) tmpExc[i] = s[threadIdx.x] - v;   // exclusive
    if (threadIdx.x == SCAN_B - 1) blockSums[blockIdx.x] = s[SCAN_B - 1];
}

// ---------------- scan pass 2: scan the block sums (single block) ----------------
__global__ __launch_bounds__(512) void scan2_kernel(int* __restrict__ blockSums,
                                                    int* __restrict__ blockOff) {
    __shared__ int s[512];
    int t = threadIdx.x;
    int v = (t < NB) ? blockSums[t] : 0;
    s[t] = v;
    __syncthreads();
    for (int off = 1; off < 512; off <<= 1) {
        int u = (t >= off) ? s[t - off] : 0;
        __syncthreads();
        s[t] += u;
        __syncthreads();
    }
    if (t < NB) blockOff[t] = s[t] - v;   // exclusive
}

// ---------------- scan pass 3: combine, write offsets + cursor ----------------
__global__ __launch_bounds__(SCAN_B) void scan3_kernel(const int* __restrict__ tmpExc,
                                                       const int* __restrict__ blockOff,
                                                       int* __restrict__ offsets,
                                                       int* __restrict__ cursor) {
    int i = blockIdx.x * SCAN_B + threadIdx.x;
    if (i < N_NODES) {
        int o = tmpExc[i] + blockOff[blockIdx.x];
        offsets[i] = o;
        cursor[i]  = o;
    }
}

// ---------------- fill CSR ----------------
__global__ __launch_bounds__(256) void fill_kernel(const int* __restrict__ ei,
                                                   int* __restrict__ cursor,
                                                   int* __restrict__ csr) {
    int stride = gridDim.x * blockDim.x;
    for (int e = blockIdx.x * blockDim.x + threadIdx.x; e < N_EDGES; e += stride) {
        int src = ei[e];
        int dst = ei[N_EDGES + e];
        int pos = atomicAdd(&cursor[dst], 1);
        csr[pos] = src;
    }
}

// ---------------- fused gather + mean + dual matmul + bias + ReLU ----------------
// One wave handles 4 consecutive nodes. W_l, W_r, b_l staged in LDS.
#define ROWS_PER_WAVE 4
__global__ __launch_bounds__(256) void fused_kernel(const float* __restrict__ x,
                                                    const int*   __restrict__ offsets,
                                                    const int*   __restrict__ deg,
                                                    const int*   __restrict__ csr,
                                                    const float* __restrict__ Wl,
                                                    const float* __restrict__ bl,
                                                    const float* __restrict__ Wr,
                                                    float* __restrict__ out) {
    __shared__ float sWl[D * D];
    __shared__ float sWr[D * D];
    __shared__ float sbl[D];
    for (int i = threadIdx.x; i < D * D; i += blockDim.x) {
        sWl[i] = Wl[i];
        sWr[i] = Wr[i];
    }
    if (threadIdx.x < D) sbl[threadIdx.x] = bl[threadIdx.x];
    __syncthreads();

    const int lane = threadIdx.x & 63;
    const int wid  = (blockIdx.x * blockDim.x + threadIdx.x) >> 6;
    const int node0 = wid * ROWS_PER_WAVE;
    if (node0 >= N_NODES) return;

    float m[ROWS_PER_WAVE];    // mean_nbr rows
    float xv[ROWS_PER_WAVE];   // self rows

    #pragma unroll
    for (int r = 0; r < ROWS_PER_WAVE; ++r) {
        const int node = node0 + r;
        float macc = 0.0f;
        float dc   = 0.0f;
        if (node < N_NODES) {
            const int start = offsets[node];
            const int dcnt  = deg[node];
            dc = (float)dcnt;
            for (int b2 = 0; b2 < dcnt; b2 += 64) {
                int si = (b2 + lane < dcnt) ? csr[start + b2 + lane] : 0;
                int nj = (dcnt - b2 < 64) ? (dcnt - b2) : 64;
                for (int j = 0; j < nj; ++j) {
                    int s2 = __builtin_amdgcn_readlane(si, j);
                    macc += x[s2 * D + lane];
                }
            }
            xv[r] = x[node * D + lane];
        } else {
            xv[r] = 0.0f;
        }
        m[r] = macc * (1.0f / fmaxf(dc, 1.0f));
    }

    float acc[ROWS_PER_WAVE];
    #pragma unroll
    for (int r = 0; r < ROWS_PER_WAVE; ++r) acc[r] = sbl[lane];

    #pragma unroll
    for (int k = 0; k < D; ++k) {
        const float wl = sWl[k * D + lane];
        const float wr = sWr[k * D + lane];
        #pragma unroll
        for (int r = 0; r < ROWS_PER_WAVE; ++r) {
            const float mk = lane_read_f(m[r], k);
            const float xk = lane_read_f(xv[r], k);
            acc[r] += mk * wl + xk * wr;
        }
    }

    #pragma unroll
    for (int r = 0; r < ROWS_PER_WAVE; ++r) {
        const int node = node0 + r;
        if (node < N_NODES) out[node * D + lane] = fmaxf(acc[r], 0.0f);
    }
}

// ---------------- launch ----------------
extern "C" void kernel_launch(void* const* d_in, const int* in_sizes, int n_in,
                              void* d_out, int out_size, void* d_ws, size_t ws_size,
                              hipStream_t stream) {
    const float* x  = (const float*)d_in[0];
    const int*   ei = (const int*)d_in[1];    // [2, N_EDGES] flat: src then dst
    const float* Wl = (const float*)d_in[2];
    const float* bl = (const float*)d_in[3];
    const float* Wr = (const float*)d_in[4];
    float* out = (float*)d_out;

    // workspace layout (ints)
    int* deg       = (int*)d_ws;               // N_NODES
    int* tmpExc    = deg + N_NODES;            // N_NODES
    int* blockSums = tmpExc + N_NODES;         // 512
    int* blockOff  = blockSums + 512;          // 512
    int* offsets   = blockOff + 512;           // N_NODES
    int* cursor    = offsets + N_NODES;        // N_NODES
    int* csr       = cursor + N_NODES;         // N_EDGES

    hipMemsetAsync(deg, 0, N_NODES * sizeof(int), stream);

    hist_kernel<<<2048, 256, 0, stream>>>(ei, deg);
    scan1_kernel<<<NB, SCAN_B, 0, stream>>>(deg, tmpExc, blockSums);
    scan2_kernel<<<1, 512, 0, stream>>>(blockSums, blockOff);
    scan3_kernel<<<NB, SCAN_B, 0, stream>>>(tmpExc, blockOff, offsets, cursor);
    fill_kernel<<<2048, 256, 0, stream>>>(ei, cursor, csr);

    {
        const int waves  = (N_NODES + ROWS_PER_WAVE - 1) / ROWS_PER_WAVE;  // 25000
        const int blocks = (waves + 3) / 4;                                 // 4 waves/block
        fused_kernel<<<blocks, 256, 0, stream>>>(x, offsets, deg, csr, Wl, bl, Wr, out);
    }
}

// Round 4
// 371.891 us; speedup vs baseline: 1.6961x; 1.3480x over previous
//
#include <hip/hip_runtime.h>

#define N_NODES 100000
#define N_EDGES 1600000
#define D 64
#define SCAN_B 256
#define NB ((N_NODES + SCAN_B - 1) / SCAN_B)   // 391

// bit-preserving float lane-broadcast (readlane keeps it off the LDS pipe)
__device__ __forceinline__ float lane_read_f(float v, int l) {
    union { float f; int i; } u; u.f = v;
    union { int i; float f; } w; w.i = __builtin_amdgcn_readlane(u.i, l);
    return w.f;
}

// ---------------- histogram of dst ----------------
__global__ __launch_bounds__(256) void hist_kernel(const int* __restrict__ ei,
                                                   int* __restrict__ deg) {
    int stride = gridDim.x * blockDim.x;
    for (int e = blockIdx.x * blockDim.x + threadIdx.x; e < N_EDGES; e += stride) {
        int dst = ei[N_EDGES + e];
        atomicAdd(&deg[dst], 1);
    }
}

// ---------------- scan pass 1: per-block exclusive scan ----------------
__global__ __launch_bounds__(SCAN_B) void scan1_kernel(const int* __restrict__ deg,
                                                       int* __restrict__ tmpExc,
                                                       int* __restrict__ blockSums) {
    __shared__ int s[SCAN_B];
    int i = blockIdx.x * SCAN_B + threadIdx.x;
    int v = (i < N_NODES) ? deg[i] : 0;
    s[threadIdx.x] = v;
    __syncthreads();
    for (int off = 1; off < SCAN_B; off <<= 1) {
        int t = (threadIdx.x >= off) ? s[threadIdx.x - off] : 0;
        __syncthreads();
        s[threadIdx.x] += t;
        __syncthreads();
    }
    if (i < N_NODES) tmpExc[i] = s[threadIdx.x] - v;   // exclusive
    if (threadIdx.x == SCAN_B - 1) blockSums[blockIdx.x] = s[SCAN_B - 1];
}

// ---------------- scan pass 2: scan the block sums (single block) ----------------
__global__ __launch_bounds__(512) void scan2_kernel(int* __restrict__ blockSums,
                                                    int* __restrict__ blockOff) {
    __shared__ int s[512];
    int t = threadIdx.x;
    int v = (t < NB) ? blockSums[t] : 0;
    s[t] = v;
    __syncthreads();
    for (int off = 1; off < 512; off <<= 1) {
        int u = (t >= off) ? s[t - off] : 0;
        __syncthreads();
        s[t] += u;
        __syncthreads();
    }
    if (t < NB) blockOff[t] = s[t] - v;   // exclusive
}

// ---------------- scan pass 3: combine, write offsets + cursor ----------------
__global__ __launch_bounds__(SCAN_B) void scan3_kernel(const int* __restrict__ tmpExc,
                                                       const int* __restrict__ blockOff,
                                                       int* __restrict__ offsets,
                                                       int* __restrict__ cursor) {
    int i = blockIdx.x * SCAN_B + threadIdx.x;
    if (i < N_NODES) {
        int o = tmpExc[i] + blockOff[blockIdx.x];
        offsets[i] = o;
        cursor[i]  = o;
    }
}

// ---------------- fill CSR ----------------
__global__ __launch_bounds__(256) void fill_kernel(const int* __restrict__ ei,
                                                   int* __restrict__ cursor,
                                                   int* __restrict__ csr) {
    int stride = gridDim.x * blockDim.x;
    for (int e = blockIdx.x * blockDim.x + threadIdx.x; e < N_EDGES; e += stride) {
        int src = ei[e];
        int dst = ei[N_EDGES + e];
        int pos = atomicAdd(&cursor[dst], 1);
        csr[pos] = src;
    }
}

// ---------------- fused gather + mean + dual matmul + bias + ReLU ----------------
// 1024-thread blocks (16 waves share the 33 KB W-stage -> LDS no longer caps
// occupancy). One wave handles 4 consecutive nodes; edge gather unrolled x8
// for 8 outstanding global loads.
#define ROWS_PER_WAVE 4
#define BLK 1024
__global__ __launch_bounds__(BLK) void fused_kernel(const float* __restrict__ x,
                                                    const int*   __restrict__ offsets,
                                                    const int*   __restrict__ deg,
                                                    const int*   __restrict__ csr,
                                                    const float* __restrict__ Wl,
                                                    const float* __restrict__ bl,
                                                    const float* __restrict__ Wr,
                                                    float* __restrict__ out) {
    __shared__ float sWl[D * D];
    __shared__ float sWr[D * D];
    __shared__ float sbl[D];
    for (int i = threadIdx.x; i < D * D; i += blockDim.x) {
        sWl[i] = Wl[i];
        sWr[i] = Wr[i];
    }
    if (threadIdx.x < D) sbl[threadIdx.x] = bl[threadIdx.x];
    __syncthreads();

    const int lane = threadIdx.x & 63;
    const int wid  = (blockIdx.x * BLK + threadIdx.x) >> 6;
    const int node0 = wid * ROWS_PER_WAVE;
    if (node0 >= N_NODES) return;

    const float* __restrict__ xl = x + lane;

    float m[ROWS_PER_WAVE];    // mean_nbr rows
    float xv[ROWS_PER_WAVE];   // self rows

    #pragma unroll
    for (int r = 0; r < ROWS_PER_WAVE; ++r) {
        const int node = node0 + r;
        float macc = 0.0f;
        float dc   = 0.0f;
        if (node < N_NODES) {
            const int start = offsets[node];
            const int dcnt  = deg[node];
            dc = (float)dcnt;
            for (int b2 = 0; b2 < dcnt; b2 += 64) {
                int si = (b2 + lane < dcnt) ? csr[start + b2 + lane] : 0;
                int nj = (dcnt - b2 < 64) ? (dcnt - b2) : 64;
                int j = 0;
                // 8 outstanding loads per iteration
                for (; j + 8 <= nj; j += 8) {
                    int s0 = __builtin_amdgcn_readlane(si, j + 0);
                    int s1 = __builtin_amdgcn_readlane(si, j + 1);
                    int s2 = __builtin_amdgcn_readlane(si, j + 2);
                    int s3 = __builtin_amdgcn_readlane(si, j + 3);
                    int s4 = __builtin_amdgcn_readlane(si, j + 4);
                    int s5 = __builtin_amdgcn_readlane(si, j + 5);
                    int s6 = __builtin_amdgcn_readlane(si, j + 6);
                    int s7 = __builtin_amdgcn_readlane(si, j + 7);
                    float v0 = xl[s0 * D];
                    float v1 = xl[s1 * D];
                    float v2 = xl[s2 * D];
                    float v3 = xl[s3 * D];
                    float v4 = xl[s4 * D];
                    float v5 = xl[s5 * D];
                    float v6 = xl[s6 * D];
                    float v7 = xl[s7 * D];
                    macc += ((v0 + v1) + (v2 + v3)) + ((v4 + v5) + (v6 + v7));
                }
                for (; j < nj; ++j) {
                    int sj = __builtin_amdgcn_readlane(si, j);
                    macc += xl[sj * D];
                }
            }
            xv[r] = xl[node * D];
        } else {
            xv[r] = 0.0f;
        }
        m[r] = macc * (1.0f / fmaxf(dc, 1.0f));
    }

    float acc[ROWS_PER_WAVE];
    #pragma unroll
    for (int r = 0; r < ROWS_PER_WAVE; ++r) acc[r] = sbl[lane];

    #pragma unroll
    for (int k = 0; k < D; ++k) {
        const float wl = sWl[k * D + lane];
        const float wr = sWr[k * D + lane];
        #pragma unroll
        for (int r = 0; r < ROWS_PER_WAVE; ++r) {
            const float mk = lane_read_f(m[r], k);
            const float xk = lane_read_f(xv[r], k);
            acc[r] += mk * wl + xk * wr;
        }
    }

    #pragma unroll
    for (int r = 0; r < ROWS_PER_WAVE; ++r) {
        const int node = node0 + r;
        if (node < N_NODES) out[node * D + lane] = fmaxf(acc[r], 0.0f);
    }
}

// ---------------- launch ----------------
extern "C" void kernel_launch(void* const* d_in, const int* in_sizes, int n_in,
                              void* d_out, int out_size, void* d_ws, size_t ws_size,
                              hipStream_t stream) {
    const float* x  = (const float*)d_in[0];
    const int*   ei = (const int*)d_in[1];    // [2, N_EDGES] flat: src then dst
    const float* Wl = (const float*)d_in[2];
    const float* bl = (const float*)d_in[3];
    const float* Wr = (const float*)d_in[4];
    float* out = (float*)d_out;

    // workspace layout (ints)
    int* deg       = (int*)d_ws;               // N_NODES
    int* tmpExc    = deg + N_NODES;            // N_NODES
    int* blockSums = tmpExc + N_NODES;         // 512
    int* blockOff  = blockSums + 512;          // 512
    int* offsets   = blockOff + 512;           // N_NODES
    int* cursor    = offsets + N_NODES;        // N_NODES
    int* csr       = cursor + N_NODES;         // N_EDGES

    hipMemsetAsync(deg, 0, N_NODES * sizeof(int), stream);

    hist_kernel<<<2048, 256, 0, stream>>>(ei, deg);
    scan1_kernel<<<NB, SCAN_B, 0, stream>>>(deg, tmpExc, blockSums);
    scan2_kernel<<<1, 512, 0, stream>>>(blockSums, blockOff);
    scan3_kernel<<<NB, SCAN_B, 0, stream>>>(tmpExc, blockOff, offsets, cursor);
    fill_kernel<<<2048, 256, 0, stream>>>(ei, cursor, csr);

    {
        const int waves  = (N_NODES + ROWS_PER_WAVE - 1) / ROWS_PER_WAVE;  // 25000
        const int waves_per_block = BLK / 64;                               // 16
        const int blocks = (waves + waves_per_block - 1) / waves_per_block; // 1563
        fused_kernel<<<blocks, BLK, 0, stream>>>(x, offsets, deg, csr, Wl, bl, Wr, out);
    }
}

// Round 5
// 249.917 us; speedup vs baseline: 2.5239x; 1.4881x over previous
//
#include <hip/hip_runtime.h>

#define N_NODES 100000
#define N_EDGES 1600000
#define D 64
#define SCAN_B 256
#define NB ((N_NODES + SCAN_B - 1) / SCAN_B)   // 391

// bit-preserving float lane-broadcast
__device__ __forceinline__ float lane_read_f(float v, int l) {
    union { float f; int i; } u; u.f = v;
    union { int i; float f; } w; w.i = __builtin_amdgcn_readlane(u.i, l);
    return w.f;
}
__device__ __forceinline__ unsigned short f2bf(float f) {
    union { float f; unsigned u; } v; v.f = f;
    unsigned r = v.u + 0x7FFFu + ((v.u >> 16) & 1u);
    return (unsigned short)(r >> 16);
}
__device__ __forceinline__ float bf2f(unsigned short h) {
    union { unsigned u; float f; } v; v.u = ((unsigned)h) << 16;
    return v.f;
}

// ---------------- histogram of dst + per-edge rank ----------------
__global__ __launch_bounds__(256) void hist_kernel(const int* __restrict__ ei,
                                                   int* __restrict__ deg,
                                                   unsigned short* __restrict__ rank) {
    int i = blockIdx.x * blockDim.x + threadIdx.x;     // 4 edges per thread
    if (i >= N_EDGES / 4) return;
    int4 d4 = ((const int4*)(ei + N_EDGES))[i];
    unsigned r0 = (unsigned)atomicAdd(&deg[d4.x], 1);
    unsigned r1 = (unsigned)atomicAdd(&deg[d4.y], 1);
    unsigned r2 = (unsigned)atomicAdd(&deg[d4.z], 1);
    unsigned r3 = (unsigned)atomicAdd(&deg[d4.w], 1);
    uint2 packed;
    packed.x = (r0 & 0xFFFFu) | (r1 << 16);
    packed.y = (r2 & 0xFFFFu) | (r3 << 16);
    ((uint2*)rank)[i] = packed;
}

// ---------------- scan pass 1 ----------------
__global__ __launch_bounds__(SCAN_B) void scan1_kernel(const int* __restrict__ deg,
                                                       int* __restrict__ tmpExc,
                                                       int* __restrict__ blockSums) {
    __shared__ int s[SCAN_B];
    int i = blockIdx.x * SCAN_B + threadIdx.x;
    int v = (i < N_NODES) ? deg[i] : 0;
    s[threadIdx.x] = v;
    __syncthreads();
    for (int off = 1; off < SCAN_B; off <<= 1) {
        int t = (threadIdx.x >= off) ? s[threadIdx.x - off] : 0;
        __syncthreads();
        s[threadIdx.x] += t;
        __syncthreads();
    }
    if (i < N_NODES) tmpExc[i] = s[threadIdx.x] - v;
    if (threadIdx.x == SCAN_B - 1) blockSums[blockIdx.x] = s[SCAN_B - 1];
}

// ---------------- scan pass 2 (single block) ----------------
__global__ __launch_bounds__(512) void scan2_kernel(int* __restrict__ blockSums,
                                                    int* __restrict__ blockOff) {
    __shared__ int s[512];
    int t = threadIdx.x;
    int v = (t < NB) ? blockSums[t] : 0;
    s[t] = v;
    __syncthreads();
    for (int off = 1; off < 512; off <<= 1) {
        int u = (t >= off) ? s[t - off] : 0;
        __syncthreads();
        s[t] += u;
        __syncthreads();
    }
    if (t < NB) blockOff[t] = s[t] - v;
}

// ---------------- scan pass 3: offsets (+ sentinel) ----------------
__global__ __launch_bounds__(SCAN_B) void scan3_kernel(const int* __restrict__ tmpExc,
                                                       const int* __restrict__ blockOff,
                                                       int* __restrict__ offsets) {
    int i = blockIdx.x * SCAN_B + threadIdx.x;
    if (i < N_NODES) offsets[i] = tmpExc[i] + blockOff[blockIdx.x];
    if (blockIdx.x == 0 && threadIdx.x == 0) offsets[N_NODES] = N_EDGES;
}

// ---------------- fill CSR (non-atomic, rank-based, 4 edges/thread) ----------------
__global__ __launch_bounds__(256) void fill_kernel(const int* __restrict__ ei,
                                                   const int* __restrict__ offsets,
                                                   const unsigned short* __restrict__ rank,
                                                   int* __restrict__ csr) {
    int i = blockIdx.x * blockDim.x + threadIdx.x;
    if (i >= N_EDGES / 4) return;
    int4 s4 = ((const int4*)ei)[i];
    int4 d4 = ((const int4*)(ei + N_EDGES))[i];
    uint2 rr = ((const uint2*)rank)[i];
    csr[offsets[d4.x] + (int)(rr.x & 0xFFFFu)] = s4.x;
    csr[offsets[d4.y] + (int)(rr.x >> 16)]     = s4.y;
    csr[offsets[d4.z] + (int)(rr.y & 0xFFFFu)] = s4.z;
    csr[offsets[d4.w] + (int)(rr.y >> 16)]     = s4.w;
}

// ---------------- gather + mean (1 node per wave, bf16 output) ----------------
__global__ __launch_bounds__(256) void gather_kernel(const float* __restrict__ x,
                                                     const int* __restrict__ offsets,
                                                     const int* __restrict__ csr,
                                                     unsigned short* __restrict__ meanb) {
    const int lane = threadIdx.x & 63;
    const int node = (blockIdx.x * blockDim.x + threadIdx.x) >> 6;
    if (node >= N_NODES) return;

    const int s0 = offsets[node];
    const int s1 = offsets[node + 1];
    const int d  = s1 - s0;

    const float* __restrict__ xl = x + lane;
    float macc = 0.0f;

    for (int b = 0; b < d; b += 64) {
        const int rem = d - b;                       // >0
        const int nj  = (rem < 64) ? rem : 64;
        // clamped lane read of csr chunk (dups hit same cache line)
        int cl = lane < nj ? lane : nj - 1;
        int si = csr[s0 + b + cl];
        for (int j = 0; j < nj; j += 16) {
            float part = 0.0f;
            #pragma unroll
            for (int t = 0; t < 16; ++t) {
                int jj = j + t;
                int jc = (jj < nj) ? jj : (nj - 1);   // uniform (SALU min)
                int sidx = __builtin_amdgcn_readlane(si, jc);
                float v = xl[(size_t)sidx * D];
                part += (jj < nj) ? v : 0.0f;
            }
            macc += part;
        }
    }
    const float inv = 1.0f / fmaxf((float)d, 1.0f);
    meanb[(size_t)node * D + lane] = f2bf(macc * inv);
}

// ---------------- epilogue: dual matmul + bias + ReLU (8 rows/wave) ----------------
#define EROWS 8
#define EBLK 1024
__global__ __launch_bounds__(EBLK) void out_kernel(const float* __restrict__ x,
                                                   const unsigned short* __restrict__ meanb,
                                                   const float* __restrict__ Wl,
                                                   const float* __restrict__ bl,
                                                   const float* __restrict__ Wr,
                                                   float* __restrict__ out) {
    __shared__ float sWl[D * D];
    __shared__ float sWr[D * D];
    __shared__ float sbl[D];
    for (int i = threadIdx.x; i < D * D; i += blockDim.x) {
        sWl[i] = Wl[i];
        sWr[i] = Wr[i];
    }
    if (threadIdx.x < D) sbl[threadIdx.x] = bl[threadIdx.x];
    __syncthreads();

    const int lane = threadIdx.x & 63;
    const int wid  = (blockIdx.x * EBLK + threadIdx.x) >> 6;
    const int row0 = wid * EROWS;
    if (row0 >= N_NODES) return;

    float mf[EROWS], xf[EROWS];
    #pragma unroll
    for (int r = 0; r < EROWS; ++r) {
        const int row = row0 + r;
        if (row < N_NODES) {
            mf[r] = bf2f(meanb[(size_t)row * D + lane]);
            xf[r] = x[(size_t)row * D + lane];
        } else {
            mf[r] = 0.0f;
            xf[r] = 0.0f;
        }
    }

    float acc[EROWS];
    #pragma unroll
    for (int r = 0; r < EROWS; ++r) acc[r] = sbl[lane];

    #pragma unroll
    for (int k = 0; k < D; ++k) {
        const float wl = sWl[k * D + lane];
        const float wr = sWr[k * D + lane];
        #pragma unroll
        for (int r = 0; r < EROWS; ++r) {
            const float mk = lane_read_f(mf[r], k);
            const float xk = lane_read_f(xf[r], k);
            acc[r] += mk * wl + xk * wr;
        }
    }

    #pragma unroll
    for (int r = 0; r < EROWS; ++r) {
        const int row = row0 + r;
        if (row < N_NODES) out[(size_t)row * D + lane] = fmaxf(acc[r], 0.0f);
    }
}

// ---------------- launch ----------------
extern "C" void kernel_launch(void* const* d_in, const int* in_sizes, int n_in,
                              void* d_out, int out_size, void* d_ws, size_t ws_size,
                              hipStream_t stream) {
    const float* x  = (const float*)d_in[0];
    const int*   ei = (const int*)d_in[1];    // [2, N_EDGES] flat: src then dst
    const float* Wl = (const float*)d_in[2];
    const float* bl = (const float*)d_in[3];
    const float* Wr = (const float*)d_in[4];
    float* out = (float*)d_out;

    // workspace layout
    int* deg       = (int*)d_ws;                         // N_NODES
    int* tmpExc    = deg + N_NODES;                      // N_NODES
    int* blockSums = tmpExc + N_NODES;                   // 512
    int* blockOff  = blockSums + 512;                    // 512
    int* offsets   = blockOff + 512;                     // N_NODES + 1
    int* csr       = offsets + N_NODES + 4;              // N_EDGES
    unsigned short* rank  = (unsigned short*)(csr + N_EDGES);        // N_EDGES
    unsigned short* meanb = rank + N_EDGES;                          // N_NODES * D
    // total ≈ 0.4*3 + 6.4 + 3.2 + 12.8 ≈ 23.7 MB

    hipMemsetAsync(deg, 0, N_NODES * sizeof(int), stream);

    {
        const int work = N_EDGES / 4;                    // 400000
        const int blocks = (work + 255) / 256;           // 1563
        hist_kernel<<<blocks, 256, 0, stream>>>(ei, deg, rank);
    }
    scan1_kernel<<<NB, SCAN_B, 0, stream>>>(deg, tmpExc, blockSums);
    scan2_kernel<<<1, 512, 0, stream>>>(blockSums, blockOff);
    scan3_kernel<<<NB, SCAN_B, 0, stream>>>(tmpExc, blockOff, offsets);
    {
        const int work = N_EDGES / 4;
        const int blocks = (work + 255) / 256;
        fill_kernel<<<blocks, 256, 0, stream>>>(ei, offsets, rank, csr);
    }
    {
        const int waves = N_NODES;                       // 1 node per wave
        const int blocks = (waves * 64 + 255) / 256;     // 25000
        gather_kernel<<<blocks, 256, 0, stream>>>(x, offsets, csr, meanb);
    }
    {
        const int waves = (N_NODES + EROWS - 1) / EROWS;             // 12500
        const int blocks = (waves * 64 + EBLK - 1) / EBLK;           // 782
        out_kernel<<<blocks, EBLK, 0, stream>>>(x, meanb, Wl, bl, Wr, out);
    }
}

// Round 6
// 214.096 us; speedup vs baseline: 2.9461x; 1.1673x over previous
//
#include <hip/hip_runtime.h>

#define N_NODES 100000
#define N_EDGES 1600000
#define D 64
#define SCAN_B 256
#define NB ((N_NODES + SCAN_B - 1) / SCAN_B)   // 391

typedef __attribute__((ext_vector_type(8))) short bf16x8;
typedef __attribute__((ext_vector_type(4))) float f32x4;

__device__ __forceinline__ unsigned short f2bf(float f) {
    union { float f; unsigned u; } v; v.f = f;
    unsigned r = v.u + 0x7FFFu + ((v.u >> 16) & 1u);
    return (unsigned short)(r >> 16);
}
__device__ __forceinline__ float bf2f_u(unsigned h) {   // low 16 bits -> float
    union { unsigned u; float f; } v; v.u = h << 16;
    return v.f;
}

// ---------------- x -> bf16 convert ----------------
__global__ __launch_bounds__(256) void cvt_kernel(const float* __restrict__ x,
                                                  unsigned short* __restrict__ xb) {
    int i = blockIdx.x * blockDim.x + threadIdx.x;     // 4 floats per thread
    if (i >= (N_NODES * D) / 4) return;
    float4 v = ((const float4*)x)[i];
    ushort4 o;
    o.x = f2bf(v.x); o.y = f2bf(v.y); o.z = f2bf(v.z); o.w = f2bf(v.w);
    ((ushort4*)xb)[i] = o;
}

// ---------------- histogram of dst + per-edge rank ----------------
__global__ __launch_bounds__(256) void hist_kernel(const int* __restrict__ ei,
                                                   int* __restrict__ deg,
                                                   unsigned short* __restrict__ rank) {
    int i = blockIdx.x * blockDim.x + threadIdx.x;     // 4 edges per thread
    if (i >= N_EDGES / 4) return;
    int4 d4 = ((const int4*)(ei + N_EDGES))[i];
    unsigned r0 = (unsigned)atomicAdd(&deg[d4.x], 1);
    unsigned r1 = (unsigned)atomicAdd(&deg[d4.y], 1);
    unsigned r2 = (unsigned)atomicAdd(&deg[d4.z], 1);
    unsigned r3 = (unsigned)atomicAdd(&deg[d4.w], 1);
    uint2 packed;
    packed.x = (r0 & 0xFFFFu) | (r1 << 16);
    packed.y = (r2 & 0xFFFFu) | (r3 << 16);
    ((uint2*)rank)[i] = packed;
}

// ---------------- scan pass 1 ----------------
__global__ __launch_bounds__(SCAN_B) void scan1_kernel(const int* __restrict__ deg,
                                                       int* __restrict__ tmpExc,
                                                       int* __restrict__ blockSums) {
    __shared__ int s[SCAN_B];
    int i = blockIdx.x * SCAN_B + threadIdx.x;
    int v = (i < N_NODES) ? deg[i] : 0;
    s[threadIdx.x] = v;
    __syncthreads();
    for (int off = 1; off < SCAN_B; off <<= 1) {
        int t = (threadIdx.x >= off) ? s[threadIdx.x - off] : 0;
        __syncthreads();
        s[threadIdx.x] += t;
        __syncthreads();
    }
    if (i < N_NODES) tmpExc[i] = s[threadIdx.x] - v;
    if (threadIdx.x == SCAN_B - 1) blockSums[blockIdx.x] = s[SCAN_B - 1];
}

// ---------------- scan pass 2 (single block) ----------------
__global__ __launch_bounds__(512) void scan2_kernel(int* __restrict__ blockSums,
                                                    int* __restrict__ blockOff) {
    __shared__ int s[512];
    int t = threadIdx.x;
    int v = (t < NB) ? blockSums[t] : 0;
    s[t] = v;
    __syncthreads();
    for (int off = 1; off < 512; off <<= 1) {
        int u = (t >= off) ? s[t - off] : 0;
        __syncthreads();
        s[t] += u;
        __syncthreads();
    }
    if (t < NB) blockOff[t] = s[t] - v;
}

// ---------------- scan pass 3: offsets (+ sentinel) ----------------
__global__ __launch_bounds__(SCAN_B) void scan3_kernel(const int* __restrict__ tmpExc,
                                                       const int* __restrict__ blockOff,
                                                       int* __restrict__ offsets) {
    int i = blockIdx.x * SCAN_B + threadIdx.x;
    if (i < N_NODES) offsets[i] = tmpExc[i] + blockOff[blockIdx.x];
    if (blockIdx.x == 0 && threadIdx.x == 0) offsets[N_NODES] = N_EDGES;
}

// ---------------- fill CSR (non-atomic, rank-based) ----------------
__global__ __launch_bounds__(256) void fill_kernel(const int* __restrict__ ei,
                                                   const int* __restrict__ offsets,
                                                   const unsigned short* __restrict__ rank,
                                                   int* __restrict__ csr) {
    int i = blockIdx.x * blockDim.x + threadIdx.x;
    if (i >= N_EDGES / 4) return;
    int4 s4 = ((const int4*)ei)[i];
    int4 d4 = ((const int4*)(ei + N_EDGES))[i];
    uint2 rr = ((const uint2*)rank)[i];
    csr[offsets[d4.x] + (int)(rr.x & 0xFFFFu)] = s4.x;
    csr[offsets[d4.y] + (int)(rr.x >> 16)]     = s4.y;
    csr[offsets[d4.z] + (int)(rr.y & 0xFFFFu)] = s4.z;
    csr[offsets[d4.w] + (int)(rr.y >> 16)]     = s4.w;
}

// ---------------- fused gather + mean + MFMA matmul + bias + ReLU ----------------
// 512-thread blocks = 8 waves. Each wave owns 16 nodes:
//   gather: 2 edges per dword load (lanes<32: even edge, lanes>=32: odd edge;
//           each lane holds cols (2c,2c+1) as a bf16 pair)
//   A-tile [16 rows][K=128] bf16 in LDS (mean cols 0..63 | self x cols 64..127),
//   XOR-swizzled; W^T stacked [Wl;Wr] -> sWt[col][k] bf16, XOR-swizzled.
//   4 col-tiles x 4 K-chunks of mfma_f32_16x16x32_bf16.
#define NPW 16
#define SBLK 512
__global__ __launch_bounds__(SBLK) void sage_kernel(const unsigned short* __restrict__ xb,
                                                    const int* __restrict__ offsets,
                                                    const int* __restrict__ csr,
                                                    const float* __restrict__ Wl,
                                                    const float* __restrict__ bl,
                                                    const float* __restrict__ Wr,
                                                    float* __restrict__ out) {
    __shared__ unsigned short sWt[D * 2 * D];      // 64 cols x 128 k, 16 KB
    __shared__ float sbl[D];
    __shared__ unsigned int sA32[(SBLK / 64) * NPW * (2 * D / 2)];  // 8 waves x 16 rows x 64 uints

    const int tid = threadIdx.x;
    // stage W^T (stacked, transposed, bf16, xor-swizzled)
    for (int i = tid; i < D * D; i += SBLK) {
        int k = i >> 6, c = i & 63;
        int swz = (c & 7) << 3;                     // ushort-index xor
        sWt[(c * 128 + k) ^ swz]      = f2bf(Wl[i]);
        sWt[(c * 128 + 64 + k) ^ swz] = f2bf(Wr[i]);
    }
    if (tid < D) sbl[tid] = bl[tid];
    __syncthreads();

    const int lane = tid & 63;
    const int wib  = tid >> 6;                      // wave in block
    const int wid  = (blockIdx.x * (SBLK / 64)) + wib;
    const int node0 = wid * NPW;
    if (node0 >= N_NODES) return;

    const unsigned int* __restrict__ xb32 = (const unsigned int*)xb;
    unsigned int* sAw = sA32 + wib * (NPW * 64);    // this wave's A-tile (uint units)
    const int lc = lane & 31;

    // ---- gather phase: 16 nodes ----
    for (int r = 0; r < NPW; ++r) {
        const int node = node0 + r;
        const int s0 = offsets[node];
        const int s1 = offsets[node + 1];
        const int d  = s1 - s0;

        unsigned int vself = xb32[node * 32 + lc];  // self row (bf16 pair), hoisted

        float a0 = 0.0f, a1 = 0.0f;
        for (int base = 0; base < d; base += 64) {
            const int nj = ((d - base) < 64) ? (d - base) : 64;
            const int cl = (lane < nj) ? lane : (nj - 1);
            const int si = csr[s0 + base + cl];
            int j = 0;
            for (; j + 16 <= nj; j += 16) {
                #pragma unroll
                for (int t = 0; t < 8; ++t) {
                    int slo = __builtin_amdgcn_readlane(si, j + 2 * t);
                    int shi = __builtin_amdgcn_readlane(si, j + 2 * t + 1);
                    int sel = (lane >= 32) ? shi : slo;
                    unsigned int v = xb32[sel * 32 + lc];
                    a0 += bf2f_u(v & 0xFFFFu);
                    a1 += bf2f_u(v >> 16);
                }
            }
            for (; j < nj; j += 2) {
                int slo = __builtin_amdgcn_readlane(si, j);
                int shi = __builtin_amdgcn_readlane(si, (j + 1 < nj) ? (j + 1) : j);
                int sel = (lane >= 32) ? shi : slo;
                unsigned int v = xb32[sel * 32 + lc];
                bool ok = (lane < 32) || (j + 1 < nj);
                a0 += ok ? bf2f_u(v & 0xFFFFu) : 0.0f;
                a1 += ok ? bf2f_u(v >> 16)     : 0.0f;
            }
        }
        // combine even-edge half (lanes<32) with odd-edge half (lanes>=32)
        a0 += __shfl_xor(a0, 32, 64);
        a1 += __shfl_xor(a1, 32, 64);
        const float inv = 1.0f / fmaxf((float)d, 1.0f);
        unsigned int mpack = ((unsigned int)f2bf(a1 * inv) << 16) | f2bf(a0 * inv);

        const int swz = (r & 7) << 2;               // uint-index xor (= byte xor (r&7)<<4)
        if (lane < 32) sAw[(r * 64 + lc) ^ swz]      = mpack;   // mean -> k 0..63
        else           sAw[(r * 64 + 32 + lc) ^ swz] = vself;   // self -> k 64..127
    }

    // ---- MFMA phase ----
    const unsigned short* sAu = (const unsigned short*)sAw;
    const int row = lane & 15;
    const int kb  = lane >> 4;                      // k-block 0..3

    bf16x8 afr[4];
    #pragma unroll
    for (int kc = 0; kc < 4; ++kc) {
        int us = (row * 128 + kc * 32 + kb * 8) ^ ((row & 7) << 3);
        afr[kc] = *(const bf16x8*)(sAu + us);
    }

    #pragma unroll
    for (int ct = 0; ct < 4; ++ct) {
        const int col = ct * 16 + row;
        f32x4 acc = {0.0f, 0.0f, 0.0f, 0.0f};
        #pragma unroll
        for (int kc = 0; kc < 4; ++kc) {
            int us = (col * 128 + kc * 32 + kb * 8) ^ ((col & 7) << 3);
            bf16x8 bfr = *(const bf16x8*)(sWt + us);
            acc = __builtin_amdgcn_mfma_f32_16x16x32_bf16(afr[kc], bfr, acc, 0, 0, 0);
        }
        const float bias = sbl[col];
        const int crow0 = (lane >> 4) * 4;
        #pragma unroll
        for (int i = 0; i < 4; ++i) {
            out[(node0 + crow0 + i) * D + col] = fmaxf(acc[i] + bias, 0.0f);
        }
    }
}

// ---------------- launch ----------------
extern "C" void kernel_launch(void* const* d_in, const int* in_sizes, int n_in,
                              void* d_out, int out_size, void* d_ws, size_t ws_size,
                              hipStream_t stream) {
    const float* x  = (const float*)d_in[0];
    const int*   ei = (const int*)d_in[1];    // [2, N_EDGES] flat: src then dst
    const float* Wl = (const float*)d_in[2];
    const float* bl = (const float*)d_in[3];
    const float* Wr = (const float*)d_in[4];
    float* out = (float*)d_out;

    // workspace layout (~23.6 MB)
    int* deg       = (int*)d_ws;                         // N_NODES
    int* tmpExc    = deg + N_NODES;                      // N_NODES
    int* blockSums = tmpExc + N_NODES;                   // 512
    int* blockOff  = blockSums + 512;                    // 512
    int* offsets   = blockOff + 512;                     // N_NODES + 1 (+pad)
    int* csr       = offsets + N_NODES + 4;              // N_EDGES
    unsigned short* rank = (unsigned short*)(csr + N_EDGES);   // N_EDGES
    unsigned short* xb   = rank + N_EDGES;                     // N_NODES * D

    hipMemsetAsync(deg, 0, N_NODES * sizeof(int), stream);

    {
        const int work = (N_NODES * D) / 4;              // 1.6M
        cvt_kernel<<<(work + 255) / 256, 256, 0, stream>>>(x, xb);
    }
    {
        const int work = N_EDGES / 4;                    // 400000
        hist_kernel<<<(work + 255) / 256, 256, 0, stream>>>(ei, deg, rank);
    }
    scan1_kernel<<<NB, SCAN_B, 0, stream>>>(deg, tmpExc, blockSums);
    scan2_kernel<<<1, 512, 0, stream>>>(blockSums, blockOff);
    scan3_kernel<<<NB, SCAN_B, 0, stream>>>(tmpExc, blockOff, offsets);
    {
        const int work = N_EDGES / 4;
        fill_kernel<<<(work + 255) / 256, 256, 0, stream>>>(ei, offsets, rank, csr);
    }
    {
        const int waves  = (N_NODES + NPW - 1) / NPW;               // 6250
        const int blocks = (waves + (SBLK / 64) - 1) / (SBLK / 64); // 782
        sage_kernel<<<blocks, SBLK, 0, stream>>>(xb, offsets, csr, Wl, bl, Wr, out);
    }
}

// Round 7
// 181.903 us; speedup vs baseline: 3.4675x; 1.1770x over previous
//
#include <hip/hip_runtime.h>

#define N_NODES 100000
#define N_EDGES 1600000
#define D 64
#define SCAN_B 256
#define NB ((N_NODES + SCAN_B - 1) / SCAN_B)   // 391

typedef __attribute__((ext_vector_type(8))) short bf16x8;
typedef __attribute__((ext_vector_type(4))) float f32x4;

__device__ __forceinline__ unsigned short f2bf(float f) {
    union { float f; unsigned u; } v; v.f = f;
    unsigned r = v.u + 0x7FFFu + ((v.u >> 16) & 1u);
    return (unsigned short)(r >> 16);
}
__device__ __forceinline__ float bf2f_u(unsigned h) {   // low 16 bits -> float
    union { unsigned u; float f; } v; v.u = h << 16;
    return v.f;
}

// ---------------- x -> bf16 convert ----------------
__global__ __launch_bounds__(256) void cvt_kernel(const float* __restrict__ x,
                                                  unsigned short* __restrict__ xb) {
    int i = blockIdx.x * blockDim.x + threadIdx.x;     // 4 floats per thread
    if (i >= (N_NODES * D) / 4) return;
    float4 v = ((const float4*)x)[i];
    ushort4 o;
    o.x = f2bf(v.x); o.y = f2bf(v.y); o.z = f2bf(v.z); o.w = f2bf(v.w);
    ((ushort4*)xb)[i] = o;
}

// ---------------- histogram of dst + per-edge rank ----------------
__global__ __launch_bounds__(256) void hist_kernel(const int* __restrict__ ei,
                                                   int* __restrict__ deg,
                                                   unsigned short* __restrict__ rank) {
    int i = blockIdx.x * blockDim.x + threadIdx.x;     // 4 edges per thread
    if (i >= N_EDGES / 4) return;
    int4 d4 = ((const int4*)(ei + N_EDGES))[i];
    unsigned r0 = (unsigned)atomicAdd(&deg[d4.x], 1);
    unsigned r1 = (unsigned)atomicAdd(&deg[d4.y], 1);
    unsigned r2 = (unsigned)atomicAdd(&deg[d4.z], 1);
    unsigned r3 = (unsigned)atomicAdd(&deg[d4.w], 1);
    uint2 packed;
    packed.x = (r0 & 0xFFFFu) | (r1 << 16);
    packed.y = (r2 & 0xFFFFu) | (r3 << 16);
    ((uint2*)rank)[i] = packed;
}

// ---------------- scan pass 1 ----------------
__global__ __launch_bounds__(SCAN_B) void scan1_kernel(const int* __restrict__ deg,
                                                       int* __restrict__ tmpExc,
                                                       int* __restrict__ blockSums) {
    __shared__ int s[SCAN_B];
    int i = blockIdx.x * SCAN_B + threadIdx.x;
    int v = (i < N_NODES) ? deg[i] : 0;
    s[threadIdx.x] = v;
    __syncthreads();
    for (int off = 1; off < SCAN_B; off <<= 1) {
        int t = (threadIdx.x >= off) ? s[threadIdx.x - off] : 0;
        __syncthreads();
        s[threadIdx.x] += t;
        __syncthreads();
    }
    if (i < N_NODES) tmpExc[i] = s[threadIdx.x] - v;
    if (threadIdx.x == SCAN_B - 1) blockSums[blockIdx.x] = s[SCAN_B - 1];
}

// ---------------- scan pass 2 (single block) ----------------
__global__ __launch_bounds__(512) void scan2_kernel(int* __restrict__ blockSums,
                                                    int* __restrict__ blockOff) {
    __shared__ int s[512];
    int t = threadIdx.x;
    int v = (t < NB) ? blockSums[t] : 0;
    s[t] = v;
    __syncthreads();
    for (int off = 1; off < 512; off <<= 1) {
        int u = (t >= off) ? s[t - off] : 0;
        __syncthreads();
        s[t] += u;
        __syncthreads();
    }
    if (t < NB) blockOff[t] = s[t] - v;
}

// ---------------- scan pass 3: offsets (+ sentinel) ----------------
__global__ __launch_bounds__(SCAN_B) void scan3_kernel(const int* __restrict__ tmpExc,
                                                       const int* __restrict__ blockOff,
                                                       int* __restrict__ offsets) {
    int i = blockIdx.x * SCAN_B + threadIdx.x;
    if (i < N_NODES) offsets[i] = tmpExc[i] + blockOff[blockIdx.x];
    if (blockIdx.x == 0 && threadIdx.x == 0) offsets[N_NODES] = N_EDGES;
}

// ---------------- fill CSR (non-atomic, rank-based) ----------------
__global__ __launch_bounds__(256) void fill_kernel(const int* __restrict__ ei,
                                                   const int* __restrict__ offsets,
                                                   const unsigned short* __restrict__ rank,
                                                   int* __restrict__ csr) {
    int i = blockIdx.x * blockDim.x + threadIdx.x;
    if (i >= N_EDGES / 4) return;
    int4 s4 = ((const int4*)ei)[i];
    int4 d4 = ((const int4*)(ei + N_EDGES))[i];
    uint2 rr = ((const uint2*)rank)[i];
    csr[offsets[d4.x] + (int)(rr.x & 0xFFFFu)] = s4.x;
    csr[offsets[d4.y] + (int)(rr.x >> 16)]     = s4.y;
    csr[offsets[d4.z] + (int)(rr.y & 0xFFFFu)] = s4.z;
    csr[offsets[d4.w] + (int)(rr.y >> 16)]     = s4.w;
}

// 8 clamp-masked edge-pairs: lanes<32 take edge jj, lanes>=32 take edge jj+1,
// each lane holds 2 cols as a packed bf16 pair. Clamped indices keep loads
// uniform (dups hit the just-used cache line); masked to 0 before accumulate.
#define STEP8(SI, J, N, A0, A1)                                              \
    {                                                                         \
        _Pragma("unroll")                                                     \
        for (int t_ = 0; t_ < 8; ++t_) {                                      \
            const int jj_  = (J) + 2 * t_;                                    \
            const int jlo_ = (jj_     < (N)) ? jj_     : ((N) - 1);           \
            const int jhi_ = (jj_ + 1 < (N)) ? jj_ + 1 : ((N) - 1);           \
            const int slo_ = __builtin_amdgcn_readlane((SI), jlo_);           \
            const int shi_ = __builtin_amdgcn_readlane((SI), jhi_);           \
            const int sel_ = (lane >= 32) ? shi_ : slo_;                      \
            unsigned v_ = xb32[(size_t)sel_ * 32 + lc];                       \
            const bool ok_ = (lane < 32) ? (jj_ < (N)) : (jj_ + 1 < (N));     \
            v_ = ok_ ? v_ : 0u;                                               \
            (A0) += bf2f_u(v_ & 0xFFFFu);                                     \
            (A1) += bf2f_u(v_ >> 16);                                         \
        }                                                                     \
    }

// rare tail for degree > 64
#define TAILCH(S0, DD, A0, A1)                                               \
    for (int base_ = 64; base_ < (DD); base_ += 64) {                        \
        const int n2_ = ((DD) - base_ < 64) ? ((DD) - base_) : 64;           \
        const int cl2_ = (lane < n2_) ? lane : (n2_ - 1);                    \
        const int sit_ = csr[(S0) + base_ + cl2_];                           \
        for (int j_ = 0; j_ < n2_; j_ += 16) { STEP8(sit_, j_, n2_, A0, A1) }\
    }

// ---------------- fused gather + mean + MFMA matmul + bias + ReLU ----------------
#define NPW 16
#define SBLK 512
__global__ __launch_bounds__(SBLK) void sage_kernel(const unsigned short* __restrict__ xb,
                                                    const int* __restrict__ offsets,
                                                    const int* __restrict__ csr,
                                                    const float* __restrict__ Wl,
                                                    const float* __restrict__ bl,
                                                    const float* __restrict__ Wr,
                                                    float* __restrict__ out) {
    __shared__ unsigned short sWt[D * 2 * D];      // 64 cols x 128 k, 16 KB
    __shared__ float sbl[D];
    __shared__ unsigned int sA32[(SBLK / 64) * NPW * (2 * D / 2)];  // 8 waves x 16 rows x 64 uints

    const int tid = threadIdx.x;
    // stage W^T (stacked, transposed, bf16, xor-swizzled)
    for (int i = tid; i < D * D; i += SBLK) {
        int k = i >> 6, c = i & 63;
        int swz = (c & 7) << 3;                     // ushort-index xor
        sWt[(c * 128 + k) ^ swz]      = f2bf(Wl[i]);
        sWt[(c * 128 + 64 + k) ^ swz] = f2bf(Wr[i]);
    }
    if (tid < D) sbl[tid] = bl[tid];
    __syncthreads();

    const int lane = tid & 63;
    const int wib  = tid >> 6;
    const int wid  = (blockIdx.x * (SBLK / 64)) + wib;
    const int node0 = wid * NPW;
    if (node0 >= N_NODES) return;

    const unsigned int* __restrict__ xb32 = (const unsigned int*)xb;
    unsigned int* sAw = sA32 + wib * (NPW * 64);
    const int lc = lane & 31;

    // ---- stage offsets for 17 boundaries with one lane-parallel load ----
    const int offl = offsets[node0 + ((lane <= NPW) ? lane : NPW)];

    // ---- stage csr chunk 0 for all 16 nodes (16 loads in flight) ----
    int si[NPW];
    int dg[NPW];
    #pragma unroll
    for (int r = 0; r < NPW; ++r) {
        const int s0 = __builtin_amdgcn_readlane(offl, r);
        const int s1 = __builtin_amdgcn_readlane(offl, r + 1);
        const int d  = s1 - s0;
        dg[r] = d;
        const int dm = (d > 0) ? d : 1;
        const int cl = (lane < dm) ? lane : (dm - 1);
        int addr = s0 + cl;
        addr = (addr < N_EDGES) ? addr : (N_EDGES - 1);
        si[r] = csr[addr];
    }

    // ---- gather: two nodes interleaved (16 xb loads in flight) ----
    #pragma unroll
    for (int p = 0; p < NPW / 2; ++p) {
        const int rA = 2 * p, rB = 2 * p + 1;
        const int dA = dg[rA], dB = dg[rB];
        const int nA = (dA < 64) ? dA : 64;
        const int nB = (dB < 64) ? dB : 64;

        const unsigned vselfA = xb32[(size_t)(node0 + rA) * 32 + lc];
        const unsigned vselfB = xb32[(size_t)(node0 + rB) * 32 + lc];

        float a0 = 0.0f, a1 = 0.0f, b0 = 0.0f, b1 = 0.0f;
        int jA = 0, jB = 0;
        while (jA < nA && jB < nB) {
            STEP8(si[rA], jA, nA, a0, a1)
            STEP8(si[rB], jB, nB, b0, b1)
            jA += 16; jB += 16;
        }
        while (jA < nA) { STEP8(si[rA], jA, nA, a0, a1) jA += 16; }
        while (jB < nB) { STEP8(si[rB], jB, nB, b0, b1) jB += 16; }
        if (dA > 64) {
            const int s0A = __builtin_amdgcn_readlane(offl, rA);
            TAILCH(s0A, dA, a0, a1)
        }
        if (dB > 64) {
            const int s0B = __builtin_amdgcn_readlane(offl, rB);
            TAILCH(s0B, dB, b0, b1)
        }

        // combine halves, pack, store A-tile rows
        a0 += __shfl_xor(a0, 32, 64);
        a1 += __shfl_xor(a1, 32, 64);
        b0 += __shfl_xor(b0, 32, 64);
        b1 += __shfl_xor(b1, 32, 64);
        const float invA = 1.0f / fmaxf((float)dA, 1.0f);
        const float invB = 1.0f / fmaxf((float)dB, 1.0f);
        const unsigned mpA = ((unsigned)f2bf(a1 * invA) << 16) | f2bf(a0 * invA);
        const unsigned mpB = ((unsigned)f2bf(b1 * invB) << 16) | f2bf(b0 * invB);
        const int swzA = (rA & 7) << 2;
        const int swzB = (rB & 7) << 2;
        if (lane < 32) {
            sAw[(rA * 64 + lc) ^ swzA] = mpA;
            sAw[(rB * 64 + lc) ^ swzB] = mpB;
        } else {
            sAw[(rA * 64 + 32 + lc) ^ swzA] = vselfA;
            sAw[(rB * 64 + 32 + lc) ^ swzB] = vselfB;
        }
    }

    // ---- MFMA phase ----
    const unsigned short* sAu = (const unsigned short*)sAw;
    const int row = lane & 15;
    const int kb  = lane >> 4;

    bf16x8 afr[4];
    #pragma unroll
    for (int kc = 0; kc < 4; ++kc) {
        int us = (row * 128 + kc * 32 + kb * 8) ^ ((row & 7) << 3);
        afr[kc] = *(const bf16x8*)(sAu + us);
    }

    #pragma unroll
    for (int ct = 0; ct < 4; ++ct) {
        const int col = ct * 16 + row;
        f32x4 acc = {0.0f, 0.0f, 0.0f, 0.0f};
        #pragma unroll
        for (int kc = 0; kc < 4; ++kc) {
            int us = (col * 128 + kc * 32 + kb * 8) ^ ((col & 7) << 3);
            bf16x8 bfr = *(const bf16x8*)(sWt + us);
            acc = __builtin_amdgcn_mfma_f32_16x16x32_bf16(afr[kc], bfr, acc, 0, 0, 0);
        }
        const float bias = sbl[col];
        const int crow0 = (lane >> 4) * 4;
        #pragma unroll
        for (int i = 0; i < 4; ++i) {
            out[(node0 + crow0 + i) * D + col] = fmaxf(acc[i] + bias, 0.0f);
        }
    }
}

// ---------------- launch ----------------
extern "C" void kernel_launch(void* const* d_in, const int* in_sizes, int n_in,
                              void* d_out, int out_size, void* d_ws, size_t ws_size,
                              hipStream_t stream) {
    const float* x  = (const float*)d_in[0];
    const int*   ei = (const int*)d_in[1];    // [2, N_EDGES] flat: src then dst
    const float* Wl = (const float*)d_in[2];
    const float* bl = (const float*)d_in[3];
    const float* Wr = (const float*)d_in[4];
    float* out = (float*)d_out;

    // workspace layout (~23.6 MB)
    int* deg       = (int*)d_ws;                         // N_NODES
    int* tmpExc    = deg + N_NODES;                      // N_NODES
    int* blockSums = tmpExc + N_NODES;                   // 512
    int* blockOff  = blockSums + 512;                    // 512
    int* offsets   = blockOff + 512;                     // N_NODES + 1 (+pad)
    int* csr       = offsets + N_NODES + 4;              // N_EDGES
    unsigned short* rank = (unsigned short*)(csr + N_EDGES);   // N_EDGES
    unsigned short* xb   = rank + N_EDGES;                     // N_NODES * D

    hipMemsetAsync(deg, 0, N_NODES * sizeof(int), stream);

    {
        const int work = (N_NODES * D) / 4;
        cvt_kernel<<<(work + 255) / 256, 256, 0, stream>>>(x, xb);
    }
    {
        const int work = N_EDGES / 4;
        hist_kernel<<<(work + 255) / 256, 256, 0, stream>>>(ei, deg, rank);
    }
    scan1_kernel<<<NB, SCAN_B, 0, stream>>>(deg, tmpExc, blockSums);
    scan2_kernel<<<1, 512, 0, stream>>>(blockSums, blockOff);
    scan3_kernel<<<NB, SCAN_B, 0, stream>>>(tmpExc, blockOff, offsets);
    {
        const int work = N_EDGES / 4;
        fill_kernel<<<(work + 255) / 256, 256, 0, stream>>>(ei, offsets, rank, csr);
    }
    {
        const int waves  = (N_NODES + NPW - 1) / NPW;               // 6250
        const int blocks = (waves + (SBLK / 64) - 1) / (SBLK / 64); // 782
        sage_kernel<<<blocks, SBLK, 0, stream>>>(xb, offsets, csr, Wl, bl, Wr, out);
    }
}

// Round 8
// 180.366 us; speedup vs baseline: 3.4971x; 1.0085x over previous
//
#include <hip/hip_runtime.h>

#define N_NODES 100000
#define N_EDGES 1600000
#define D 64

typedef __attribute__((ext_vector_type(8))) short bf16x8;
typedef __attribute__((ext_vector_type(4))) float f32x4;

__device__ __forceinline__ unsigned short f2bf(float f) {
    union { float f; unsigned u; } v; v.f = f;
    unsigned r = v.u + 0x7FFFu + ((v.u >> 16) & 1u);
    return (unsigned short)(r >> 16);
}
__device__ __forceinline__ float bf2f_u(unsigned h) {   // low 16 bits -> float
    union { unsigned u; float f; } v; v.u = h << 16;
    return v.f;
}

// ---------------- fused x->bf16 convert + dst histogram/rank ----------------
#define CVT_ITEMS ((N_NODES * D) / 4)     // 1,600,000 float4 items
#define HIST_ITEMS (N_EDGES / 4)          //   400,000 int4 items
__global__ __launch_bounds__(256) void cvthist_kernel(const float* __restrict__ x,
                                                      unsigned short* __restrict__ xb,
                                                      const int* __restrict__ ei,
                                                      int* __restrict__ deg,
                                                      unsigned short* __restrict__ rank) {
    int i = blockIdx.x * blockDim.x + threadIdx.x;
    if (i < CVT_ITEMS) {
        float4 v = ((const float4*)x)[i];
        ushort4 o;
        o.x = f2bf(v.x); o.y = f2bf(v.y); o.z = f2bf(v.z); o.w = f2bf(v.w);
        ((ushort4*)xb)[i] = o;
    } else if (i < CVT_ITEMS + HIST_ITEMS) {
        int j = i - CVT_ITEMS;
        int4 d4 = ((const int4*)(ei + N_EDGES))[j];
        unsigned r0 = (unsigned)atomicAdd(&deg[d4.x], 1);
        unsigned r1 = (unsigned)atomicAdd(&deg[d4.y], 1);
        unsigned r2 = (unsigned)atomicAdd(&deg[d4.z], 1);
        unsigned r3 = (unsigned)atomicAdd(&deg[d4.w], 1);
        uint2 packed;
        packed.x = (r0 & 0xFFFFu) | (r1 << 16);
        packed.y = (r2 & 0xFFFFu) | (r3 << 16);
        ((uint2*)rank)[j] = packed;
    }
}

// ---------------- single-kernel decoupled-lookback exclusive scan ----------------
#define SCAN_TPB 256
#define SCAN_VPT 4
#define SCAN_TILE (SCAN_TPB * SCAN_VPT)                     // 1024
#define SCAN_NBK ((N_NODES + SCAN_TILE - 1) / SCAN_TILE)    // 98
// state[b] = (flag<<32) | value ; flag: 0=invalid, 1=aggregate, 2=inclusive prefix
__global__ __launch_bounds__(SCAN_TPB) void scan_kernel(const int* __restrict__ deg,
                                                        int* __restrict__ offsets,
                                                        unsigned long long* __restrict__ state) {
    __shared__ int sums[SCAN_TPB];
    __shared__ int sPrefix;
    const int tid = threadIdx.x;
    const int b   = blockIdx.x;
    const int base = b * SCAN_TILE + tid * SCAN_VPT;

    int4 v = {0, 0, 0, 0};
    if (base + 3 < N_NODES) {
        v = *(const int4*)(deg + base);
    } else {
        if (base     < N_NODES) v.x = deg[base];
        if (base + 1 < N_NODES) v.y = deg[base + 1];
        if (base + 2 < N_NODES) v.z = deg[base + 2];
        if (base + 3 < N_NODES) v.w = deg[base + 3];
    }
    const int tsum = v.x + v.y + v.z + v.w;

    sums[tid] = tsum;
    __syncthreads();
    for (int off = 1; off < SCAN_TPB; off <<= 1) {
        int t = (tid >= off) ? sums[tid - off] : 0;
        __syncthreads();
        sums[tid] += t;
        __syncthreads();
    }
    const int incl = sums[tid];
    const int excl = incl - tsum;
    const int agg  = sums[SCAN_TPB - 1];

    if (tid == 0) {
        unsigned long long pub =
            (((unsigned long long)((b == 0) ? 2u : 1u)) << 32) | (unsigned)agg;
        __hip_atomic_store(&state[b], pub, __ATOMIC_RELEASE, __HIP_MEMORY_SCOPE_AGENT);
    }

    if (b > 0) {
        if (tid < 64) {
            const int lane = tid;
            int running = 0;
            int idx = b - 1;
            while (true) {
                const int look = idx - lane;
                unsigned long long s = 0;
                if (look >= 0) {
                    do {
                        s = __hip_atomic_load(&state[look], __ATOMIC_ACQUIRE,
                                              __HIP_MEMORY_SCOPE_AGENT);
                    } while ((s >> 32) == 0);
                }
                unsigned long long bal = __ballot(look >= 0 && (s >> 32) == 2u);
                if (bal) {
                    const int fp = __ffsll((unsigned long long)bal) - 1;  // nearest prefix
                    int val = (look >= 0 && lane <= fp) ? (int)(unsigned)s : 0;
                    #pragma unroll
                    for (int o = 1; o < 64; o <<= 1) val += __shfl_xor(val, o, 64);
                    running += val;
                    break;
                } else {
                    int val = (look >= 0) ? (int)(unsigned)s : 0;
                    #pragma unroll
                    for (int o = 1; o < 64; o <<= 1) val += __shfl_xor(val, o, 64);
                    running += val;
                    idx -= 64;
                    if (idx < 0) break;
                }
            }
            if (lane == 0) {
                sPrefix = running;
                unsigned long long pub =
                    (2ULL << 32) | (unsigned)(running + agg);
                __hip_atomic_store(&state[b], pub, __ATOMIC_RELEASE,
                                   __HIP_MEMORY_SCOPE_AGENT);
            }
        }
    } else {
        if (tid == 0) sPrefix = 0;
    }
    __syncthreads();

    const int o0 = sPrefix + excl;
    if (base + 3 < N_NODES) {
        int4 w;
        w.x = o0;
        w.y = o0 + v.x;
        w.z = o0 + v.x + v.y;
        w.w = o0 + v.x + v.y + v.z;
        *(int4*)(offsets + base) = w;
    } else {
        if (base     < N_NODES) offsets[base]     = o0;
        if (base + 1 < N_NODES) offsets[base + 1] = o0 + v.x;
        if (base + 2 < N_NODES) offsets[base + 2] = o0 + v.x + v.y;
        if (base + 3 < N_NODES) offsets[base + 3] = o0 + v.x + v.y + v.z;
    }
    if (b == SCAN_NBK - 1 && tid == SCAN_TPB - 1) offsets[N_NODES] = N_EDGES;
}

// ---------------- fill CSR (non-atomic, rank-based) ----------------
__global__ __launch_bounds__(256) void fill_kernel(const int* __restrict__ ei,
                                                   const int* __restrict__ offsets,
                                                   const unsigned short* __restrict__ rank,
                                                   int* __restrict__ csr) {
    int i = blockIdx.x * blockDim.x + threadIdx.x;
    if (i >= N_EDGES / 4) return;
    int4 s4 = ((const int4*)ei)[i];
    int4 d4 = ((const int4*)(ei + N_EDGES))[i];
    uint2 rr = ((const uint2*)rank)[i];
    csr[offsets[d4.x] + (int)(rr.x & 0xFFFFu)] = s4.x;
    csr[offsets[d4.y] + (int)(rr.x >> 16)]     = s4.y;
    csr[offsets[d4.z] + (int)(rr.y & 0xFFFFu)] = s4.z;
    csr[offsets[d4.w] + (int)(rr.y >> 16)]     = s4.w;
}

// 8 clamp-masked edge-pairs: lanes<32 take edge jj, lanes>=32 take edge jj+1,
// each lane holds 2 cols as a packed bf16 pair.
#define STEP8(SI, J, N, A0, A1)                                              \
    {                                                                         \
        _Pragma("unroll")                                                     \
        for (int t_ = 0; t_ < 8; ++t_) {                                      \
            const int jj_  = (J) + 2 * t_;                                    \
            const int jlo_ = (jj_     < (N)) ? jj_     : ((N) - 1);           \
            const int jhi_ = (jj_ + 1 < (N)) ? jj_ + 1 : ((N) - 1);           \
            const int slo_ = __builtin_amdgcn_readlane((SI), jlo_);           \
            const int shi_ = __builtin_amdgcn_readlane((SI), jhi_);           \
            const int sel_ = (lane >= 32) ? shi_ : slo_;                      \
            unsigned v_ = xb32[(size_t)sel_ * 32 + lc];                       \
            const bool ok_ = (lane < 32) ? (jj_ < (N)) : (jj_ + 1 < (N));     \
            v_ = ok_ ? v_ : 0u;                                               \
            (A0) += bf2f_u(v_ & 0xFFFFu);                                     \
            (A1) += bf2f_u(v_ >> 16);                                         \
        }                                                                     \
    }

// rare tail for degree > 64
#define TAILCH(S0, DD, A0, A1)                                               \
    for (int base_ = 64; base_ < (DD); base_ += 64) {                        \
        const int n2_ = ((DD) - base_ < 64) ? ((DD) - base_) : 64;           \
        const int cl2_ = (lane < n2_) ? lane : (n2_ - 1);                    \
        const int sit_ = csr[(S0) + base_ + cl2_];                           \
        for (int j_ = 0; j_ < n2_; j_ += 16) { STEP8(sit_, j_, n2_, A0, A1) }\
    }

// ---------------- fused gather + mean + MFMA matmul + bias + ReLU ----------------
#define NPW 16
#define SBLK 512
__global__ __launch_bounds__(SBLK) void sage_kernel(const unsigned short* __restrict__ xb,
                                                    const int* __restrict__ offsets,
                                                    const int* __restrict__ csr,
                                                    const float* __restrict__ Wl,
                                                    const float* __restrict__ bl,
                                                    const float* __restrict__ Wr,
                                                    float* __restrict__ out) {
    __shared__ unsigned short sWt[D * 2 * D];      // 64 cols x 128 k, 16 KB
    __shared__ float sbl[D];
    __shared__ unsigned int sA32[(SBLK / 64) * NPW * (2 * D / 2)];  // 8 waves x 16 rows x 64 uints

    const int tid = threadIdx.x;
    for (int i = tid; i < D * D; i += SBLK) {
        int k = i >> 6, c = i & 63;
        int swz = (c & 7) << 3;                     // ushort-index xor
        sWt[(c * 128 + k) ^ swz]      = f2bf(Wl[i]);
        sWt[(c * 128 + 64 + k) ^ swz] = f2bf(Wr[i]);
    }
    if (tid < D) sbl[tid] = bl[tid];
    __syncthreads();

    const int lane = tid & 63;
    const int wib  = tid >> 6;
    const int wid  = (blockIdx.x * (SBLK / 64)) + wib;
    const int node0 = wid * NPW;
    if (node0 >= N_NODES) return;

    const unsigned int* __restrict__ xb32 = (const unsigned int*)xb;
    unsigned int* sAw = sA32 + wib * (NPW * 64);
    const int lc = lane & 31;

    // ---- stage offsets for 17 boundaries with one lane-parallel load ----
    const int offl = offsets[node0 + ((lane <= NPW) ? lane : NPW)];

    // ---- stage csr chunk 0 for all 16 nodes (16 loads in flight) ----
    int si[NPW];
    int dg[NPW];
    #pragma unroll
    for (int r = 0; r < NPW; ++r) {
        const int s0 = __builtin_amdgcn_readlane(offl, r);
        const int s1 = __builtin_amdgcn_readlane(offl, r + 1);
        const int d  = s1 - s0;
        dg[r] = d;
        const int dm = (d > 0) ? d : 1;
        const int cl = (lane < dm) ? lane : (dm - 1);
        int addr = s0 + cl;
        addr = (addr < N_EDGES) ? addr : (N_EDGES - 1);
        si[r] = csr[addr];
    }

    // ---- gather: two nodes interleaved (16 xb loads in flight) ----
    #pragma unroll
    for (int p = 0; p < NPW / 2; ++p) {
        const int rA = 2 * p, rB = 2 * p + 1;
        const int dA = dg[rA], dB = dg[rB];
        const int nA = (dA < 64) ? dA : 64;
        const int nB = (dB < 64) ? dB : 64;

        const unsigned vselfA = xb32[(size_t)(node0 + rA) * 32 + lc];
        const unsigned vselfB = xb32[(size_t)(node0 + rB) * 32 + lc];

        float a0 = 0.0f, a1 = 0.0f, b0 = 0.0f, b1 = 0.0f;
        int jA = 0, jB = 0;
        while (jA < nA && jB < nB) {
            STEP8(si[rA], jA, nA, a0, a1)
            STEP8(si[rB], jB, nB, b0, b1)
            jA += 16; jB += 16;
        }
        while (jA < nA) { STEP8(si[rA], jA, nA, a0, a1) jA += 16; }
        while (jB < nB) { STEP8(si[rB], jB, nB, b0, b1) jB += 16; }
        if (dA > 64) {
            const int s0A = __builtin_amdgcn_readlane(offl, rA);
            TAILCH(s0A, dA, a0, a1)
        }
        if (dB > 64) {
            const int s0B = __builtin_amdgcn_readlane(offl, rB);
            TAILCH(s0B, dB, b0, b1)
        }

        a0 += __shfl_xor(a0, 32, 64);
        a1 += __shfl_xor(a1, 32, 64);
        b0 += __shfl_xor(b0, 32, 64);
        b1 += __shfl_xor(b1, 32, 64);
        const float invA = 1.0f / fmaxf((float)dA, 1.0f);
        const float invB = 1.0f / fmaxf((float)dB, 1.0f);
        const unsigned mpA = ((unsigned)f2bf(a1 * invA) << 16) | f2bf(a0 * invA);
        const unsigned mpB = ((unsigned)f2bf(b1 * invB) << 16) | f2bf(b0 * invB);
        const int swzA = (rA & 7) << 2;
        const int swzB = (rB & 7) << 2;
        if (lane < 32) {
            sAw[(rA * 64 + lc) ^ swzA] = mpA;
            sAw[(rB * 64 + lc) ^ swzB] = mpB;
        } else {
            sAw[(rA * 64 + 32 + lc) ^ swzA] = vselfA;
            sAw[(rB * 64 + 32 + lc) ^ swzB] = vselfB;
        }
    }

    // ---- MFMA phase ----
    const unsigned short* sAu = (const unsigned short*)sAw;
    const int row = lane & 15;
    const int kb  = lane >> 4;

    bf16x8 afr[4];
    #pragma unroll
    for (int kc = 0; kc < 4; ++kc) {
        int us = (row * 128 + kc * 32 + kb * 8) ^ ((row & 7) << 3);
        afr[kc] = *(const bf16x8*)(sAu + us);
    }

    #pragma unroll
    for (int ct = 0; ct < 4; ++ct) {
        const int col = ct * 16 + row;
        f32x4 acc = {0.0f, 0.0f, 0.0f, 0.0f};
        #pragma unroll
        for (int kc = 0; kc < 4; ++kc) {
            int us = (col * 128 + kc * 32 + kb * 8) ^ ((col & 7) << 3);
            bf16x8 bfr = *(const bf16x8*)(sWt + us);
            acc = __builtin_amdgcn_mfma_f32_16x16x32_bf16(afr[kc], bfr, acc, 0, 0, 0);
        }
        const float bias = sbl[col];
        const int crow0 = (lane >> 4) * 4;
        #pragma unroll
        for (int i = 0; i < 4; ++i) {
            out[(node0 + crow0 + i) * D + col] = fmaxf(acc[i] + bias, 0.0f);
        }
    }
}

// ---------------- launch ----------------
extern "C" void kernel_launch(void* const* d_in, const int* in_sizes, int n_in,
                              void* d_out, int out_size, void* d_ws, size_t ws_size,
                              hipStream_t stream) {
    const float* x  = (const float*)d_in[0];
    const int*   ei = (const int*)d_in[1];    // [2, N_EDGES] flat: src then dst
    const float* Wl = (const float*)d_in[2];
    const float* bl = (const float*)d_in[3];
    const float* Wr = (const float*)d_in[4];
    float* out = (float*)d_out;

    // workspace layout (~23.2 MB), 16B-aligned segments
    int* deg = (int*)d_ws;                                         // N_NODES (400000 B)
    unsigned long long* state = (unsigned long long*)(deg + N_NODES);  // 98 (pad to 1024 B)
    int* offsets = (int*)((char*)state + 1024);                    // N_NODES + 1 (+pad to 16B)
    int* csr = offsets + N_NODES + 4;                              // N_EDGES
    unsigned short* rank = (unsigned short*)(csr + N_EDGES);       // N_EDGES
    unsigned short* xb   = rank + N_EDGES;                         // N_NODES * D

    // zero deg + scan state flags in one memset
    hipMemsetAsync(deg, 0, N_NODES * sizeof(int) + 1024, stream);

    {
        const int items = CVT_ITEMS + HIST_ITEMS;                  // 2,000,000
        cvthist_kernel<<<(items + 255) / 256, 256, 0, stream>>>(x, xb, ei, deg, rank);
    }
    scan_kernel<<<SCAN_NBK, SCAN_TPB, 0, stream>>>(deg, offsets, state);
    {
        const int work = N_EDGES / 4;
        fill_kernel<<<(work + 255) / 256, 256, 0, stream>>>(ei, offsets, rank, csr);
    }
    {
        const int waves  = (N_NODES + NPW - 1) / NPW;               // 6250
        const int blocks = (waves + (SBLK / 64) - 1) / (SBLK / 64); // 782
        sage_kernel<<<blocks, SBLK, 0, stream>>>(xb, offsets, csr, Wl, bl, Wr, out);
    }
}

// Round 9
// 178.900 us; speedup vs baseline: 3.5257x; 1.0082x over previous
//
#include <hip/hip_runtime.h>

#define N_NODES 100000
#define N_EDGES 1600000
#define D 64
#define P 4
#define CBROW (N_NODES + 4)               // cbase row stride (p=0 row == offsets)

typedef __attribute__((ext_vector_type(8))) short bf16x8;
typedef __attribute__((ext_vector_type(4))) float f32x4;

__device__ __forceinline__ unsigned short f2bf(float f) {
    union { float f; unsigned u; } v; v.f = f;
    unsigned r = v.u + 0x7FFFu + ((v.u >> 16) & 1u);
    return (unsigned short)(r >> 16);
}
__device__ __forceinline__ float bf2f_u(unsigned h) {   // low 16 bits -> float
    union { unsigned u; float f; } v; v.u = h << 16;
    return v.f;
}

// ---------------- fused dst histogram/rank (first) + x->bf16 convert ----------------
#define CVT_ITEMS ((N_NODES * D) / 4)     // 1,600,000 float4 items
#define HIST_ITEMS (N_EDGES / 4)          //   400,000 int4 items
__global__ __launch_bounds__(256) void cvthist_kernel(const float* __restrict__ x,
                                                      unsigned short* __restrict__ xb,
                                                      const int* __restrict__ ei,
                                                      int* __restrict__ degp,
                                                      unsigned short* __restrict__ rank) {
    int i = blockIdx.x * blockDim.x + threadIdx.x;
    if (i < HIST_ITEMS) {
        int4 d4 = ((const int4*)(ei + N_EDGES))[i];
        int* dp = degp + (size_t)(i & (P - 1)) * N_NODES;
        unsigned r0 = (unsigned)atomicAdd(&dp[d4.x], 1);
        unsigned r1 = (unsigned)atomicAdd(&dp[d4.y], 1);
        unsigned r2 = (unsigned)atomicAdd(&dp[d4.z], 1);
        unsigned r3 = (unsigned)atomicAdd(&dp[d4.w], 1);
        uint2 packed;
        packed.x = (r0 & 0xFFFFu) | (r1 << 16);
        packed.y = (r2 & 0xFFFFu) | (r3 << 16);
        ((uint2*)rank)[i] = packed;
    } else if (i < HIST_ITEMS + CVT_ITEMS) {
        int j = i - HIST_ITEMS;
        float4 v = ((const float4*)x)[j];
        ushort4 o;
        o.x = f2bf(v.x); o.y = f2bf(v.y); o.z = f2bf(v.z); o.w = f2bf(v.w);
        ((ushort4*)xb)[j] = o;
    }
}

// ---------------- single-kernel decoupled-lookback scan over node totals ----------------
// Emits cbase[p][n] = offsets[n] + sum_{p'<p} degp[p'][n]; row p=0 == offsets.
#define SCAN_TPB 256
#define SCAN_VPT 4
#define SCAN_TILE (SCAN_TPB * SCAN_VPT)                     // 1024
#define SCAN_NBK ((N_NODES + SCAN_TILE - 1) / SCAN_TILE)    // 98
__global__ __launch_bounds__(SCAN_TPB) void scan_kernel(const int* __restrict__ degp,
                                                        int* __restrict__ cbase,
                                                        unsigned long long* __restrict__ state) {
    __shared__ int sums[SCAN_TPB];
    __shared__ int sPrefix;
    const int tid = threadIdx.x;
    const int b   = blockIdx.x;
    const int base = b * SCAN_TILE + tid * SCAN_VPT;

    int4 t0 = {0,0,0,0}, t1 = {0,0,0,0}, t2 = {0,0,0,0}, t3 = {0,0,0,0};
    if (base + 3 < N_NODES) {
        t0 = *(const int4*)(degp + 0 * N_NODES + base);
        t1 = *(const int4*)(degp + 1 * N_NODES + base);
        t2 = *(const int4*)(degp + 2 * N_NODES + base);
        t3 = *(const int4*)(degp + 3 * N_NODES + base);
    } else {
        if (base     < N_NODES) { t0.x = degp[base];     t1.x = degp[N_NODES+base];     t2.x = degp[2*N_NODES+base];     t3.x = degp[3*N_NODES+base]; }
        if (base + 1 < N_NODES) { t0.y = degp[base+1];   t1.y = degp[N_NODES+base+1];   t2.y = degp[2*N_NODES+base+1];   t3.y = degp[3*N_NODES+base+1]; }
        if (base + 2 < N_NODES) { t0.z = degp[base+2];   t1.z = degp[N_NODES+base+2];   t2.z = degp[2*N_NODES+base+2];   t3.z = degp[3*N_NODES+base+2]; }
        if (base + 3 < N_NODES) { t0.w = degp[base+3];   t1.w = degp[N_NODES+base+3];   t2.w = degp[2*N_NODES+base+3];   t3.w = degp[3*N_NODES+base+3]; }
    }
    int4 tot;
    tot.x = t0.x + t1.x + t2.x + t3.x;
    tot.y = t0.y + t1.y + t2.y + t3.y;
    tot.z = t0.z + t1.z + t2.z + t3.z;
    tot.w = t0.w + t1.w + t2.w + t3.w;
    const int tsum = tot.x + tot.y + tot.z + tot.w;

    sums[tid] = tsum;
    __syncthreads();
    for (int off = 1; off < SCAN_TPB; off <<= 1) {
        int t = (tid >= off) ? sums[tid - off] : 0;
        __syncthreads();
        sums[tid] += t;
        __syncthreads();
    }
    const int incl = sums[tid];
    const int excl = incl - tsum;
    const int agg  = sums[SCAN_TPB - 1];

    if (tid == 0) {
        unsigned long long pub =
            (((unsigned long long)((b == 0) ? 2u : 1u)) << 32) | (unsigned)agg;
        __hip_atomic_store(&state[b], pub, __ATOMIC_RELEASE, __HIP_MEMORY_SCOPE_AGENT);
    }

    if (b > 0) {
        if (tid < 64) {
            const int lane = tid;
            int running = 0;
            int idx = b - 1;
            while (true) {
                const int look = idx - lane;
                unsigned long long s = 0;
                if (look >= 0) {
                    do {
                        s = __hip_atomic_load(&state[look], __ATOMIC_ACQUIRE,
                                              __HIP_MEMORY_SCOPE_AGENT);
                    } while ((s >> 32) == 0);
                }
                unsigned long long bal = __ballot(look >= 0 && (s >> 32) == 2u);
                if (bal) {
                    const int fp = __ffsll((unsigned long long)bal) - 1;
                    int val = (look >= 0 && lane <= fp) ? (int)(unsigned)s : 0;
                    #pragma unroll
                    for (int o = 1; o < 64; o <<= 1) val += __shfl_xor(val, o, 64);
                    running += val;
                    break;
                } else {
                    int val = (look >= 0) ? (int)(unsigned)s : 0;
                    #pragma unroll
                    for (int o = 1; o < 64; o <<= 1) val += __shfl_xor(val, o, 64);
                    running += val;
                    idx -= 64;
                    if (idx < 0) break;
                }
            }
            if (lane == 0) {
                sPrefix = running;
                unsigned long long pub = (2ULL << 32) | (unsigned)(running + agg);
                __hip_atomic_store(&state[b], pub, __ATOMIC_RELEASE,
                                   __HIP_MEMORY_SCOPE_AGENT);
            }
        }
    } else {
        if (tid == 0) sPrefix = 0;
    }
    __syncthreads();

    // per-node offsets within thread
    const int ox = sPrefix + excl;
    const int oy = ox + tot.x;
    const int oz = oy + tot.y;
    const int ow = oz + tot.z;

    if (base + 3 < N_NODES) {
        int4 c0, c1, c2, c3;
        c0.x = ox;          c0.y = oy;          c0.z = oz;          c0.w = ow;
        c1.x = c0.x + t0.x; c1.y = c0.y + t0.y; c1.z = c0.z + t0.z; c1.w = c0.w + t0.w;
        c2.x = c1.x + t1.x; c2.y = c1.y + t1.y; c2.z = c1.z + t1.z; c2.w = c1.w + t1.w;
        c3.x = c2.x + t2.x; c3.y = c2.y + t2.y; c3.z = c2.z + t2.z; c3.w = c2.w + t2.w;
        *(int4*)(cbase + 0 * CBROW + base) = c0;
        *(int4*)(cbase + 1 * CBROW + base) = c1;
        *(int4*)(cbase + 2 * CBROW + base) = c2;
        *(int4*)(cbase + 3 * CBROW + base) = c3;
    } else {
        if (base < N_NODES) {
            cbase[0*CBROW+base] = ox; cbase[1*CBROW+base] = ox + t0.x;
            cbase[2*CBROW+base] = ox + t0.x + t1.x; cbase[3*CBROW+base] = ox + t0.x + t1.x + t2.x;
        }
        if (base + 1 < N_NODES) {
            cbase[0*CBROW+base+1] = oy; cbase[1*CBROW+base+1] = oy + t0.y;
            cbase[2*CBROW+base+1] = oy + t0.y + t1.y; cbase[3*CBROW+base+1] = oy + t0.y + t1.y + t2.y;
        }
        if (base + 2 < N_NODES) {
            cbase[0*CBROW+base+2] = oz; cbase[1*CBROW+base+2] = oz + t0.z;
            cbase[2*CBROW+base+2] = oz + t0.z + t1.z; cbase[3*CBROW+base+2] = oz + t0.z + t1.z + t2.z;
        }
        if (base + 3 < N_NODES) {
            cbase[0*CBROW+base+3] = ow; cbase[1*CBROW+base+3] = ow + t0.w;
            cbase[2*CBROW+base+3] = ow + t0.w + t1.w; cbase[3*CBROW+base+3] = ow + t0.w + t1.w + t2.w;
        }
    }
    if (b == SCAN_NBK - 1 && tid == SCAN_TPB - 1) cbase[N_NODES] = N_EDGES;  // sentinel in p=0 row
}

// ---------------- fill CSR (non-atomic, rank+cbase based) ----------------
__global__ __launch_bounds__(256) void fill_kernel(const int* __restrict__ ei,
                                                   const int* __restrict__ cbase,
                                                   const unsigned short* __restrict__ rank,
                                                   int* __restrict__ csr) {
    int i = blockIdx.x * blockDim.x + threadIdx.x;
    if (i >= N_EDGES / 4) return;
    int4 s4 = ((const int4*)ei)[i];
    int4 d4 = ((const int4*)(ei + N_EDGES))[i];
    uint2 rr = ((const uint2*)rank)[i];
    const int* cb = cbase + (size_t)(i & (P - 1)) * CBROW;
    csr[cb[d4.x] + (int)(rr.x & 0xFFFFu)] = s4.x;
    csr[cb[d4.y] + (int)(rr.x >> 16)]     = s4.y;
    csr[cb[d4.z] + (int)(rr.y & 0xFFFFu)] = s4.z;
    csr[cb[d4.w] + (int)(rr.y >> 16)]     = s4.w;
}

// 8 clamp-masked edge-pairs: lanes<32 take edge jj, lanes>=32 take edge jj+1,
// each lane holds 2 cols as a packed bf16 pair.
#define STEP8(SI, J, N, A0, A1)                                              \
    {                                                                         \
        _Pragma("unroll")                                                     \
        for (int t_ = 0; t_ < 8; ++t_) {                                      \
            const int jj_  = (J) + 2 * t_;                                    \
            const int jlo_ = (jj_     < (N)) ? jj_     : ((N) - 1);           \
            const int jhi_ = (jj_ + 1 < (N)) ? jj_ + 1 : ((N) - 1);           \
            const int slo_ = __builtin_amdgcn_readlane((SI), jlo_);           \
            const int shi_ = __builtin_amdgcn_readlane((SI), jhi_);           \
            const int sel_ = (lane >= 32) ? shi_ : slo_;                      \
            unsigned v_ = xb32[(size_t)sel_ * 32 + lc];                       \
            const bool ok_ = (lane < 32) ? (jj_ < (N)) : (jj_ + 1 < (N));     \
            v_ = ok_ ? v_ : 0u;                                               \
            (A0) += bf2f_u(v_ & 0xFFFFu);                                     \
            (A1) += bf2f_u(v_ >> 16);                                         \
        }                                                                     \
    }

// rare tail for degree > 64
#define TAILCH(S0, DD, A0, A1)                                               \
    for (int base_ = 64; base_ < (DD); base_ += 64) {                        \
        const int n2_ = ((DD) - base_ < 64) ? ((DD) - base_) : 64;           \
        const int cl2_ = (lane < n2_) ? lane : (n2_ - 1);                    \
        const int sit_ = csr[(S0) + base_ + cl2_];                           \
        for (int j_ = 0; j_ < n2_; j_ += 16) { STEP8(sit_, j_, n2_, A0, A1) }\
    }

// ---------------- fused gather + mean + MFMA matmul + bias + ReLU ----------------
#define NPW 16
#define SBLK 512
__global__ __launch_bounds__(SBLK) void sage_kernel(const unsigned short* __restrict__ xb,
                                                    const int* __restrict__ offsets,
                                                    const int* __restrict__ csr,
                                                    const float* __restrict__ Wl,
                                                    const float* __restrict__ bl,
                                                    const float* __restrict__ Wr,
                                                    float* __restrict__ out) {
    __shared__ unsigned short sWt[D * 2 * D];      // 64 cols x 128 k, 16 KB
    __shared__ float sbl[D];
    __shared__ unsigned int sA32[(SBLK / 64) * NPW * (2 * D / 2)];  // 8 waves x 16 rows x 64 uints

    const int tid = threadIdx.x;
    for (int i = tid; i < D * D; i += SBLK) {
        int k = i >> 6, c = i & 63;
        int swz = (c & 7) << 3;                     // ushort-index xor
        sWt[(c * 128 + k) ^ swz]      = f2bf(Wl[i]);
        sWt[(c * 128 + 64 + k) ^ swz] = f2bf(Wr[i]);
    }
    if (tid < D) sbl[tid] = bl[tid];
    __syncthreads();

    const int lane = tid & 63;
    const int wib  = tid >> 6;
    const int wid  = (blockIdx.x * (SBLK / 64)) + wib;
    const int node0 = wid * NPW;
    if (node0 >= N_NODES) return;

    const unsigned int* __restrict__ xb32 = (const unsigned int*)xb;
    unsigned int* sAw = sA32 + wib * (NPW * 64);
    const int lc = lane & 31;

    // ---- stage offsets for 17 boundaries with one lane-parallel load ----
    const int offl = offsets[node0 + ((lane <= NPW) ? lane : NPW)];

    // ---- stage csr chunk 0 for all 16 nodes (16 loads in flight) ----
    int si[NPW];
    int dg[NPW];
    #pragma unroll
    for (int r = 0; r < NPW; ++r) {
        const int s0 = __builtin_amdgcn_readlane(offl, r);
        const int s1 = __builtin_amdgcn_readlane(offl, r + 1);
        const int d  = s1 - s0;
        dg[r] = d;
        const int dm = (d > 0) ? d : 1;
        const int cl = (lane < dm) ? lane : (dm - 1);
        int addr = s0 + cl;
        addr = (addr < N_EDGES) ? addr : (N_EDGES - 1);
        si[r] = csr[addr];
    }

    // ---- gather: two nodes interleaved (16 xb loads in flight) ----
    #pragma unroll
    for (int p = 0; p < NPW / 2; ++p) {
        const int rA = 2 * p, rB = 2 * p + 1;
        const int dA = dg[rA], dB = dg[rB];
        const int nA = (dA < 64) ? dA : 64;
        const int nB = (dB < 64) ? dB : 64;

        const unsigned vselfA = xb32[(size_t)(node0 + rA) * 32 + lc];
        const unsigned vselfB = xb32[(size_t)(node0 + rB) * 32 + lc];

        float a0 = 0.0f, a1 = 0.0f, b0 = 0.0f, b1 = 0.0f;
        int jA = 0, jB = 0;
        while (jA < nA && jB < nB) {
            STEP8(si[rA], jA, nA, a0, a1)
            STEP8(si[rB], jB, nB, b0, b1)
            jA += 16; jB += 16;
        }
        while (jA < nA) { STEP8(si[rA], jA, nA, a0, a1) jA += 16; }
        while (jB < nB) { STEP8(si[rB], jB, nB, b0, b1) jB += 16; }
        if (dA > 64) {
            const int s0A = __builtin_amdgcn_readlane(offl, rA);
            TAILCH(s0A, dA, a0, a1)
        }
        if (dB > 64) {
            const int s0B = __builtin_amdgcn_readlane(offl, rB);
            TAILCH(s0B, dB, b0, b1)
        }

        a0 += __shfl_xor(a0, 32, 64);
        a1 += __shfl_xor(a1, 32, 64);
        b0 += __shfl_xor(b0, 32, 64);
        b1 += __shfl_xor(b1, 32, 64);
        const float invA = 1.0f / fmaxf((float)dA, 1.0f);
        const float invB = 1.0f / fmaxf((float)dB, 1.0f);
        const unsigned mpA = ((unsigned)f2bf(a1 * invA) << 16) | f2bf(a0 * invA);
        const unsigned mpB = ((unsigned)f2bf(b1 * invB) << 16) | f2bf(b0 * invB);
        const int swzA = (rA & 7) << 2;
        const int swzB = (rB & 7) << 2;
        if (lane < 32) {
            sAw[(rA * 64 + lc) ^ swzA] = mpA;
            sAw[(rB * 64 + lc) ^ swzB] = mpB;
        } else {
            sAw[(rA * 64 + 32 + lc) ^ swzA] = vselfA;
            sAw[(rB * 64 + 32 + lc) ^ swzB] = vselfB;
        }
    }

    // ---- MFMA phase ----
    const unsigned short* sAu = (const unsigned short*)sAw;
    const int row = lane & 15;
    const int kb  = lane >> 4;

    bf16x8 afr[4];
    #pragma unroll
    for (int kc = 0; kc < 4; ++kc) {
        int us = (row * 128 + kc * 32 + kb * 8) ^ ((row & 7) << 3);
        afr[kc] = *(const bf16x8*)(sAu + us);
    }

    #pragma unroll
    for (int ct = 0; ct < 4; ++ct) {
        const int col = ct * 16 + row;
        f32x4 acc = {0.0f, 0.0f, 0.0f, 0.0f};
        #pragma unroll
        for (int kc = 0; kc < 4; ++kc) {
            int us = (col * 128 + kc * 32 + kb * 8) ^ ((col & 7) << 3);
            bf16x8 bfr = *(const bf16x8*)(sWt + us);
            acc = __builtin_amdgcn_mfma_f32_16x16x32_bf16(afr[kc], bfr, acc, 0, 0, 0);
        }
        const float bias = sbl[col];
        const int crow0 = (lane >> 4) * 4;
        #pragma unroll
        for (int i = 0; i < 4; ++i) {
            out[(node0 + crow0 + i) * D + col] = fmaxf(acc[i] + bias, 0.0f);
        }
    }
}

// ---------------- launch ----------------
extern "C" void kernel_launch(void* const* d_in, const int* in_sizes, int n_in,
                              void* d_out, int out_size, void* d_ws, size_t ws_size,
                              hipStream_t stream) {
    const float* x  = (const float*)d_in[0];
    const int*   ei = (const int*)d_in[1];    // [2, N_EDGES] flat: src then dst
    const float* Wl = (const float*)d_in[2];
    const float* bl = (const float*)d_in[3];
    const float* Wr = (const float*)d_in[4];
    float* out = (float*)d_out;

    // workspace layout (~25.6 MB), 16B-aligned segments
    int* degp = (int*)d_ws;                                            // P * N_NODES (1.6 MB)
    unsigned long long* state = (unsigned long long*)(degp + P * N_NODES);  // 1 KB pad
    int* cbase = (int*)((char*)state + 1024);                          // P * CBROW (1.6 MB)
    int* csr = cbase + P * CBROW;                                      // N_EDGES (6.4 MB)
    unsigned short* rank = (unsigned short*)(csr + N_EDGES);           // N_EDGES (3.2 MB)
    unsigned short* xb   = rank + N_EDGES;                             // N_NODES * D (12.8 MB)

    // zero degp + scan state flags in one memset
    hipMemsetAsync(degp, 0, (size_t)P * N_NODES * sizeof(int) + 1024, stream);

    {
        const int items = HIST_ITEMS + CVT_ITEMS;                      // 2,000,000
        cvthist_kernel<<<(items + 255) / 256, 256, 0, stream>>>(x, xb, ei, degp, rank);
    }
    scan_kernel<<<SCAN_NBK, SCAN_TPB, 0, stream>>>(degp, cbase, state);
    {
        const int work = N_EDGES / 4;
        fill_kernel<<<(work + 255) / 256, 256, 0, stream>>>(ei, cbase, rank, csr);
    }
    {
        const int waves  = (N_NODES + NPW - 1) / NPW;               // 6250
        const int blocks = (waves + (SBLK / 64) - 1) / (SBLK / 64); // 782
        sage_kernel<<<blocks, SBLK, 0, stream>>>(xb, cbase, csr, Wl, bl, Wr, out);
    }
}